// Round 10
// baseline (17396.553 us; speedup 1.0000x reference)
//
#include <hip/hip_runtime.h>
#include <hip/hip_bf16.h>
#include <hip/hip_fp16.h>

#define BB  512
#define TT  256
#define MM  81
#define HEE 256

// ---- workspace layout (float offsets) ----
#define OFF_W2AH   0          // half2[256 k2][256 j]  encoder p1 weight pairs
#define OFF_WE8    65536      // uint4[169 k2][256 j]  encoder LSTM, gate-major pairs
#define OFF_W8D1   238592     // uint4[64 k8][256 j]   decoder p1, 8 halves k=8k8..8k8+7
#define OFF_WD8    304128     // uint4[128 k2][256 j]  decoder Whh, gate-major pairs
#define OFF_ATTN   436224     // [512][81] attn_in
#define OFF_ENCW   477696     // [512][256] enc . W_fc[:256]
#define OFF_ENC    608768     // [512][256][256] input_encoded fp32
#define OFF_EPI    34163200   // half[512 b][256 t'][256 h] enc_proj
#define WS_FLOATS  50940416

typedef _Float16 hh2 __attribute__((ext_vector_type(2)));

__device__ __forceinline__ float frcp(float x) { return __builtin_amdgcn_rcpf(x); }
__device__ __forceinline__ float fsig(float x) { return frcp(1.f + __expf(-x)); }
__device__ __forceinline__ float ftanh(float x) { return 1.f - 2.f * frcp(__expf(2.f * x) + 1.f); }
__device__ __forceinline__ hh2 uash2(unsigned int u) { union { unsigned int u; hh2 h; } x; x.u = u; return x.h; }
__device__ __forceinline__ float fdot2f(unsigned int a, unsigned int b, float c) {
#if __has_builtin(__builtin_amdgcn_fdot2)
  return __builtin_amdgcn_fdot2(uash2(a), uash2(b), c, false);
#else
  hh2 ha = uash2(a), hb = uash2(b);
  return c + (float)ha.x * (float)hb.x + (float)ha.y * (float)hb.y;
#endif
}
__device__ __forceinline__ ushort f2h(float x) { return __half_as_ushort(__float2half(x)); }

// ---------------- weight prep ----------------
__global__ void k_prep(const float* __restrict__ W_ah, const float* __restrict__ Wih_e,
                       const float* __restrict__ Whh_e, const float* __restrict__ W_d1,
                       const float* __restrict__ Wih_d, const float* __restrict__ Whh_d,
                       float* __restrict__ ws) {
  int idx = blockIdx.x * 512 + threadIdx.x;
  if (idx < 65536) {  // encoder p1 pairs
    int k2 = idx >> 8, j = idx & 255;
    ((__half2*)(ws + OFF_W2AH))[idx] =
        __floats2half2_rn(W_ah[j * 512 + 2 * k2], W_ah[j * 512 + 2 * k2 + 1]);
  }
  if (idx < 16384) {  // decoder p1: uint4[64 k8][256 j], halves k=8k8..8k8+7
    int k8 = idx >> 8, j = idx & 255;
    const float* wr = W_d1 + (size_t)j * 768 + 8 * k8;
    union { __half2 h[4]; uint4 u; } w;
    w.h[0] = __floats2half2_rn(wr[0], wr[1]);
    w.h[1] = __floats2half2_rn(wr[2], wr[3]);
    w.h[2] = __floats2half2_rn(wr[4], wr[5]);
    w.h[3] = __floats2half2_rn(wr[6], wr[7]);
    ((uint4*)(ws + OFF_W8D1))[idx] = w.u;
  }
  if (idx < 43264) {  // encoder LSTM: gate-major pairs over u=[wi(81);h(256);pad]
    int k2 = idx >> 8, j = idx & 255;
    auto we = [&](int g, int kk) -> float {
      if (kk < 81)  return Wih_e[(g * 256 + j) * 81 + kk];
      if (kk < 337) return Whh_e[(g * 256 + j) * 256 + (kk - 81)];
      return 0.f;
    };
    int ke = 2 * k2, ko = 2 * k2 + 1;
    union { __half2 h[4]; uint4 u; } w;
    w.h[0] = __floats2half2_rn(we(0, ke), we(0, ko));
    w.h[1] = __floats2half2_rn(we(1, ke), we(1, ko));
    w.h[2] = __floats2half2_rn(we(2, ke), we(2, ko));
    w.h[3] = __floats2half2_rn(we(3, ke), we(3, ko));
    ((uint4*)(ws + OFF_WE8))[idx] = w.u;
  }
  if (idx < 32768) {  // decoder Whh: gate-major pairs, 128 k2
    int k2 = idx >> 8, j = idx & 255;
    int ke = 2 * k2, ko = 2 * k2 + 1;
    union { __half2 h[4]; uint4 u; } w;
    w.h[0] = __floats2half2_rn(Whh_d[(0 * 256 + j) * 256 + ke], Whh_d[(0 * 256 + j) * 256 + ko]);
    w.h[1] = __floats2half2_rn(Whh_d[(1 * 256 + j) * 256 + ke], Whh_d[(1 * 256 + j) * 256 + ko]);
    w.h[2] = __floats2half2_rn(Whh_d[(2 * 256 + j) * 256 + ke], Whh_d[(2 * 256 + j) * 256 + ko]);
    w.h[3] = __floats2half2_rn(Whh_d[(3 * 256 + j) * 256 + ke], Whh_d[(3 * 256 + j) * 256 + ko]);
    ((uint4*)(ws + OFF_WD8))[idx] = w.u;
  }
}

// ---------------- attn_in[b][m] ----------------
__global__ void k_attn(const float* __restrict__ x, const float* __restrict__ W_ai,
                       const float* __restrict__ b_ai, float* __restrict__ ws) {
  __shared__ float wai[256];
  const int b = blockIdx.x, tid = threadIdx.x;  // 128 threads
  wai[tid] = W_ai[tid];
  wai[128 + tid] = W_ai[128 + tid];
  __syncthreads();
  if (tid < MM) {
    float acc = b_ai[0];
    const float* xp = x + (size_t)b * TT * MM + tid;
    #pragma unroll 8
    for (int t = 0; t < TT; ++t) acc = fmaf(xp[t * MM], wai[t], acc);
    ws[OFF_ATTN + b * MM + tid] = acc;
  }
}

// ---------------- encoder: unchanged from R8 ----------------
__global__ __launch_bounds__(1024, 2) void k_encoder(
    const float* __restrict__ x, const float* __restrict__ b_ah,
    const float* __restrict__ W_a, const float* __restrict__ b_a,
    const float* __restrict__ bih_e, const float* __restrict__ bhh_e,
    float* __restrict__ ws) {
  __shared__ __align__(16) float aA[2048];
  __shared__ __align__(16) float4 gA[2048];
  __shared__ __align__(16) float hpb[512];
  __shared__ __align__(16) float wa2[256];
  __shared__ __align__(16) ushort hcb[2][512];
  __shared__ __align__(16) ushort uu[2][344];
  const int tid = threadIdx.x;
  const int j = tid & 255, q = tid >> 8;
  const int b0 = blockIdx.x * 2, b1 = b0 + 1;

  if (tid < 256) wa2[tid] = W_a[tid];
  if (tid < 512) { hcb[0][tid] = 0; hcb[1][tid] = 0; }
  if (tid < 344) { uu[0][tid] = 0; uu[1][tid] = 0; }
  float bahr = 0.f; float4 bias4 = {0, 0, 0, 0};
  if (tid < 512) {
    bahr = b_ah[j];
    bias4.x = bih_e[j] + bhh_e[j];
    bias4.y = bih_e[256 + j] + bhh_e[256 + j];
    bias4.z = bih_e[512 + j] + bhh_e[512 + j];
    bias4.w = bih_e[768 + j] + bhh_e[768 + j];
  }
  float ai0 = 0.f, ai1 = 0.f;
  {
    int m = tid & 127;
    if (m < MM) {
      ai0 = ws[OFF_ATTN + b0 * MM + m];
      ai1 = ws[OFF_ATTN + b1 * MM + m];
    }
  }
  const float bav = b_a[0];
  float xc0 = 0.f, xc1 = 0.f;
  if (tid < 128) {
    int bb = (tid >= 64) ? b1 : b0;
    int lane = tid & 63;
    xc0 = x[((size_t)bb * TT) * MM + lane];
    xc1 = (lane < 17) ? x[((size_t)bb * TT) * MM + 64 + lane] : 0.f;
  }
  const unsigned int* __restrict__ Wah2u = (const unsigned int*)(ws + OFF_W2AH);
  const uint4* __restrict__ We8 = (const uint4*)(ws + OFF_WE8);
  const unsigned int* __restrict__ hc0 = (const unsigned int*)hcb[0];
  const unsigned int* __restrict__ hc1 = (const unsigned int*)hcb[1];
  const unsigned int* __restrict__ u0p = (const unsigned int*)uu[0];
  const unsigned int* __restrict__ u1p = (const unsigned int*)uu[1];
  float creg = 0.f;
  __syncthreads();

  for (int t = 0; t < TT; ++t) {
    {
      float a0 = 0.f, a1 = 0.f;
      const int kb = q * 64;
      #pragma unroll 8
      for (int i = 0; i < 64; ++i) {
        unsigned int w = Wah2u[(kb + i) * 256 + j];
        a0 = fdot2f(w, hc0[kb + i], a0);
        a1 = fdot2f(w, hc1[kb + i], a1);
      }
      aA[(q * 256 + j) * 2 + 0] = a0;
      aA[(q * 256 + j) * 2 + 1] = a1;
      float4 g0 = {0, 0, 0, 0}, g1 = {0, 0, 0, 0};
      const int ku0 = 41 + q * 32;
      #pragma unroll 4
      for (int i = 0; i < 32; ++i) {
        int ku = ku0 + i;
        uint4 wu = We8[ku * 256 + j];
        unsigned int ua = u0p[ku], ub = u1p[ku];
        g0.x = fdot2f(wu.x, ua, g0.x); g0.y = fdot2f(wu.y, ua, g0.y);
        g0.z = fdot2f(wu.z, ua, g0.z); g0.w = fdot2f(wu.w, ua, g0.w);
        g1.x = fdot2f(wu.x, ub, g1.x); g1.y = fdot2f(wu.y, ub, g1.y);
        g1.z = fdot2f(wu.z, ub, g1.z); g1.w = fdot2f(wu.w, ub, g1.w);
      }
      gA[(q * 2 + 0) * 256 + j] = g0;
      gA[(q * 2 + 1) * 256 + j] = g1;
    }
    __syncthreads();
    if (tid < 512) {
      int b = tid >> 8, h = tid & 255;
      hpb[2 * h + b] = aA[(0 * 256 + h) * 2 + b] + aA[(1 * 256 + h) * 2 + b] +
                       aA[(2 * 256 + h) * 2 + b] + aA[(3 * 256 + h) * 2 + b] + bahr;
    }
    __syncthreads();
    {
      int m = tid & 127, tq = tid >> 7;
      if (m < MM) {
        float e0 = 0.f, e1 = 0.f;
        #pragma unroll 8
        for (int i = tq * 16; i < tq * 16 + 16; ++i) {
          float4 hv = *(const float4*)&hpb[i * 4];
          float2 wv = *(const float2*)&wa2[i * 2];
          e0 += ftanh(hv.x + ai0) * wv.x + ftanh(hv.z + ai0) * wv.y;
          e1 += ftanh(hv.y + ai1) * wv.x + ftanh(hv.w + ai1) * wv.y;
        }
        aA[(tq * 2 + 0) * 96 + m] = e0;
        aA[(tq * 2 + 1) * 96 + m] = e1;
      }
    }
    __syncthreads();
    if (tid < 128) {
      int wv_id = tid >> 6, lane = tid & 63;
      float v0 = bav, v1 = bav;
      #pragma unroll
      for (int tq = 0; tq < 8; ++tq) {
        v0 += aA[(tq * 2 + wv_id) * 96 + lane];
        if (lane < 17) v1 += aA[(tq * 2 + wv_id) * 96 + 64 + lane];
      }
      float e0 = __expf(v0);
      float e1 = (lane < 17) ? __expf(v1) : 0.f;
      float sm = e0 + e1;
      #pragma unroll
      for (int d = 1; d < 64; d <<= 1) sm += __shfl_xor(sm, d);
      float inv = frcp(sm);
      uu[wv_id][lane] = f2h(e0 * inv * xc0);
      if (lane < 17) uu[wv_id][64 + lane] = f2h(e1 * inv * xc1);
      if (t < 255) {
        int bb = wv_id ? b1 : b0;
        xc0 = x[((size_t)bb * TT + t + 1) * MM + lane];
        xc1 = (lane < 17) ? x[((size_t)bb * TT + t + 1) * MM + 64 + lane] : 0.f;
      }
    }
    __syncthreads();
    {
      const int kA = (q == 0) ? 0 : (q == 1) ? 11 : (q == 2) ? 21 : 31;
      const int kB = (q == 0) ? 11 : (q == 1) ? 21 : (q == 2) ? 31 : 41;
      float4 g0 = gA[(q * 2 + 0) * 256 + j];
      float4 g1 = gA[(q * 2 + 1) * 256 + j];
      for (int ku = kA; ku < kB; ++ku) {
        uint4 wu = We8[ku * 256 + j];
        unsigned int ua = u0p[ku], ub = u1p[ku];
        g0.x = fdot2f(wu.x, ua, g0.x); g0.y = fdot2f(wu.y, ua, g0.y);
        g0.z = fdot2f(wu.z, ua, g0.z); g0.w = fdot2f(wu.w, ua, g0.w);
        g1.x = fdot2f(wu.x, ub, g1.x); g1.y = fdot2f(wu.y, ub, g1.y);
        g1.z = fdot2f(wu.z, ub, g1.z); g1.w = fdot2f(wu.w, ub, g1.w);
      }
      gA[(q * 2 + 0) * 256 + j] = g0;
      gA[(q * 2 + 1) * 256 + j] = g1;
    }
    __syncthreads();
    if (tid < 512) {
      int b = tid >> 8, jj = tid & 255;
      float4 s0 = gA[(0 * 2 + b) * 256 + jj];
      float4 s1 = gA[(1 * 2 + b) * 256 + jj];
      float4 s2 = gA[(2 * 2 + b) * 256 + jj];
      float4 s3 = gA[(3 * 2 + b) * 256 + jj];
      float gi = s0.x + s1.x + s2.x + s3.x + bias4.x;
      float gf = s0.y + s1.y + s2.y + s3.y + bias4.y;
      float gg = s0.z + s1.z + s2.z + s3.z + bias4.z;
      float go = s0.w + s1.w + s2.w + s3.w + bias4.w;
      float c = fsig(gf) * creg + fsig(gi) * ftanh(gg);
      float h = fsig(go) * ftanh(c);
      creg = c;
      hcb[b][jj] = f2h(h);
      hcb[b][256 + jj] = f2h(c);
      uu[b][81 + jj] = f2h(h);
      ws[OFF_ENC + (((size_t)(b ? b1 : b0) * TT + t) * HEE + jj)] = h;
    }
    __syncthreads();
  }
}

// ---------------- encW[b][t] = enc[b,t,:] . W_fc[:256] ----------------
__global__ __launch_bounds__(256) void k_encw(const float* __restrict__ W_fc, float* __restrict__ ws) {
  const float* __restrict__ enc = ws + OFF_ENC;
  const int wv = threadIdx.x >> 6, lane = threadIdx.x & 63;
  float4 wfc = reinterpret_cast<const float4*>(W_fc)[lane];
  for (int r = blockIdx.x * 4 + wv; r < BB * TT; r += 4096) {
    float4 e = reinterpret_cast<const float4*>(enc + (size_t)r * HEE)[lane];
    float d = e.x * wfc.x + e.y * wfc.y + e.z * wfc.z + e.w * wfc.w;
    #pragma unroll
    for (int dd = 1; dd < 64; dd <<= 1) d += __shfl_xor(d, dd);
    if (lane == 0) ws[OFF_ENCW + r] = d;
  }
}

// ---------------- enc_proj fp16: epH[b][t'][h] ----------------
__global__ __launch_bounds__(256) void k_encproj(const float* __restrict__ W_d1, float* __restrict__ ws) {
  __shared__ __align__(16) float le[16][256];
  const int tid = threadIdx.x;
  const int b = blockIdx.x >> 4;
  const int t0 = (blockIdx.x & 15) * 16;
  const float* __restrict__ enc = ws + OFF_ENC;
  __half* __restrict__ epH = (__half*)(ws + OFF_EPI);
  #pragma unroll
  for (int rr = 0; rr < 16; ++rr)
    le[rr][tid] = enc[((size_t)b * TT + (t0 + rr)) * HEE + tid];
  __syncthreads();
  const float4* wrow = (const float4*)(W_d1 + (size_t)tid * 768 + 512);
  float acc[16];
  #pragma unroll
  for (int r = 0; r < 16; ++r) acc[r] = 0.f;
  for (int e4 = 0; e4 < 64; ++e4) {
    float4 w = wrow[e4];
    #pragma unroll
    for (int r = 0; r < 16; ++r) {
      float4 ev = *(const float4*)&le[r][e4 * 4];
      acc[r] += ev.x * w.x + ev.y * w.y + ev.z * w.z + ev.w * w.w;
    }
  }
  #pragma unroll
  for (int rr = 0; rr < 16; ++rr)
    epH[((size_t)b * TT + (t0 + rr)) * HEE + tid] = __float2half(acc[rr]);
}

// ---------------- decoder: 512 WGs (1 batch each), 512 threads, ep in registers ----------------
__global__ __launch_bounds__(512, 4) void k_decoder(
    const float* __restrict__ y_history, const float* __restrict__ b_d1,
    const float* __restrict__ W_d2, const float* __restrict__ b_d2,
    const float* __restrict__ W_fc, const float* __restrict__ b_fc,
    const float* __restrict__ Wih_d,
    const float* __restrict__ bih_d, const float* __restrict__ bhh_d,
    const float* __restrict__ W_ff, const float* __restrict__ b_ff,
    float* __restrict__ ws, float* __restrict__ out) {
  __shared__ __align__(16) float aA[512];     // p1 partials (bias pre-folded): q*256+j
  __shared__ __align__(16) float sc[512];     // score partials: q*256+t'
  __shared__ __align__(16) float4 gA4[512];   // gate partials: q*256+j
  __shared__ __align__(16) ushort hc[512];    // fp16 [h(256); c(256)]
  __shared__ __align__(16) float w2f[256];
  __shared__ __align__(16) float ybuf[256];
  __shared__ __align__(16) float awls[256];
  __shared__ float red[2][4];
  const int tid = threadIdx.x;
  const int tp = tid & 255, q = tid >> 8;     // q in {0,1}
  const int lane = tid & 63, wvid = tid >> 6; // tid<256 -> wvid 0..3
  const int b = blockIdx.x;
  const float wfcy = W_fc[256], bfc = b_fc[0], bd2v = b_d2[0], bffv = b_ff[0];

  if (tid < 256) w2f[tid] = W_d2[tid];
  if (tid < 255) ybuf[tid] = y_history[(size_t)b * 255 + tid] * wfcy + bfc;
  hc[tid] = 0;
  const float bd1h = 0.5f * b_d1[tp];   // half-bias folded into each p1 partial
  float4 biasd, wy;
  biasd.x = bih_d[tp] + bhh_d[tp];
  biasd.y = bih_d[256 + tp] + bhh_d[256 + tp];
  biasd.z = bih_d[512 + tp] + bhh_d[512 + tp];
  biasd.w = bih_d[768 + tp] + bhh_d[768 + tp];
  wy.x = Wih_d[tp]; wy.y = Wih_d[256 + tp]; wy.z = Wih_d[512 + tp]; wy.w = Wih_d[768 + tp];
  const float wffh = W_ff[tp], wffc = W_ff[256 + tp];
  const float ewr = ws[OFF_ENCW + (size_t)b * 256 + tp];

  const uint4* __restrict__ W8 = (const uint4*)(ws + OFF_W8D1);
  const uint4* __restrict__ Wd8 = (const uint4*)(ws + OFF_WD8);

  // enc_proj half-row (128 h = 64 dwords = 16 uint4) in registers, static-indexed only
  uint4 ep[16];
  {
    const uint4* src = (const uint4*)(ws + OFF_EPI) + (size_t)b * 8192 + tp * 32 + q * 16;
    #pragma unroll
    for (int i = 0; i < 16; ++i) ep[i] = src[i];
  }
  __syncthreads();

  float hreg = 0.f, creg = 0.f, esc = 0.f;

  for (int s = 0; s < 255; ++s) {
    // ---- A: p1 partial (k-half q) + Whh gate partial (k-half q) ----
    {
      float a0 = bd1h;
      const uint4* hc4 = (const uint4*)hc;
      const int k8b = q * 32;
      #pragma unroll 4
      for (int i = 0; i < 32; ++i) {
        int k8 = k8b + i;
        uint4 wu = W8[k8 * 256 + tp];
        uint4 hv = hc4[k8];
        a0 = fdot2f(wu.x, hv.x, a0);
        a0 = fdot2f(wu.y, hv.y, a0);
        a0 = fdot2f(wu.z, hv.z, a0);
        a0 = fdot2f(wu.w, hv.w, a0);
      }
      aA[q * 256 + tp] = a0;
      float4 g = {0, 0, 0, 0};
      const unsigned int* hcu = (const unsigned int*)hc;
      const int k2b = q * 64;
      #pragma unroll 4
      for (int i = 0; i < 64; ++i) {
        int k2 = k2b + i;
        uint4 wu = Wd8[k2 * 256 + tp];
        unsigned int u2 = hcu[k2];
        g.x = fdot2f(wu.x, u2, g.x); g.y = fdot2f(wu.y, u2, g.y);
        g.z = fdot2f(wu.z, u2, g.z); g.w = fdot2f(wu.w, u2, g.w);
      }
      gA4[q * 256 + tp] = g;
    }
    __syncthreads();
    // ---- C: score partial over own 128 h (d combined on the fly from aA) ----
    {
      float q0 = 0.f;
      const int hb = q * 128;
      #pragma unroll
      for (int i = 0; i < 16; ++i) {
        const int h8 = hb + i * 8;
        float4 pa0 = *(const float4*)&aA[h8];
        float4 pa1 = *(const float4*)&aA[h8 + 4];
        float4 pb0 = *(const float4*)&aA[256 + h8];
        float4 pb1 = *(const float4*)&aA[256 + h8 + 4];
        float4 wf0 = *(const float4*)&w2f[h8];
        float4 wf1 = *(const float4*)&w2f[h8 + 4];
        const __half2* eh = (const __half2*)&ep[i];
        float2 e0 = __half22float2(eh[0]);
        q0 += wf0.x * ftanh(e0.x + pa0.x + pb0.x) + wf0.y * ftanh(e0.y + pa0.y + pb0.y);
        float2 e1 = __half22float2(eh[1]);
        q0 += wf0.z * ftanh(e1.x + pa0.z + pb0.z) + wf0.w * ftanh(e1.y + pa0.w + pb0.w);
        float2 e2 = __half22float2(eh[2]);
        q0 += wf1.x * ftanh(e2.x + pa1.x + pb1.x) + wf1.y * ftanh(e2.y + pa1.y + pb1.y);
        float2 e3 = __half22float2(eh[3]);
        q0 += wf1.z * ftanh(e3.x + pa1.z + pb1.z) + wf1.w * ftanh(e3.y + pa1.w + pb1.w);
      }
      sc[q * 256 + tp] = q0;
    }
    __syncthreads();
    // ---- D: softmax partial reductions (no max-shift; |score| <= ~10) ----
    if (tid < 256) {
      float v = sc[tp] + sc[256 + tp] + bd2v;
      esc = __expf(v);
      float den = esc, num = esc * ewr;
      #pragma unroll
      for (int d = 1; d < 64; d <<= 1) { den += __shfl_xor(den, d); num += __shfl_xor(num, d); }
      if (lane == 0) { red[0][wvid] = den; red[1][wvid] = num; }
    }
    __syncthreads();
    // ---- E: y + gate combine + state update ----
    if (tid < 256) {
      float den = red[0][0] + red[0][1] + red[0][2] + red[0][3];
      float num = red[1][0] + red[1][1] + red[1][2] + red[1][3];
      float inv = frcp(den);
      float y = num * inv + ybuf[s];
      if (s == 254) awls[tp] = esc * inv;
      float4 ga = gA4[tp], gb = gA4[256 + tp];
      float gi = ga.x + gb.x + wy.x * y + biasd.x;
      float gf = ga.y + gb.y + wy.y * y + biasd.y;
      float gg = ga.z + gb.z + wy.z * y + biasd.z;
      float go = ga.w + gb.w + wy.w * y + biasd.w;
      float c = fsig(gf) * creg + fsig(gi) * ftanh(gg);
      float h = fsig(go) * ftanh(c);
      creg = c; hreg = h;
      hc[tp] = f2h(h);
      hc[256 + tp] = f2h(c);
    }
    __syncthreads();
  }

  // ---- finale: ctx with last-step aw + output ----
  {
    float c0 = 0.f;
    const float* __restrict__ e32 = ws + OFF_ENC + (size_t)b * TT * HEE;
    for (int t = q * 128; t < q * 128 + 128; ++t)
      c0 = fmaf(awls[t], e32[(size_t)t * HEE + tp], c0);
    aA[q * 256 + tp] = c0;
  }
  __syncthreads();
  if (tid < 256) {
    float ctx = aA[tp] + aA[256 + tp];
    float p = hreg * wffh + ctx * wffc;
    #pragma unroll
    for (int d = 1; d < 64; d <<= 1) p += __shfl_xor(p, d);
    if (lane == 0) red[0][wvid] = p;
  }
  __syncthreads();
  if (tid == 0) out[b] = red[0][0] + red[0][1] + red[0][2] + red[0][3] + bffv;
}

extern "C" void kernel_launch(void* const* d_in, const int* in_sizes, int n_in,
                              void* d_out, int out_size, void* d_ws, size_t ws_size,
                              hipStream_t stream) {
  if (ws_size < (size_t)WS_FLOATS * sizeof(float)) return;
  const float* x     = (const float*)d_in[0];
  const float* y_h   = (const float*)d_in[1];
  const float* W_ah  = (const float*)d_in[2];
  const float* b_ah  = (const float*)d_in[3];
  const float* W_ai  = (const float*)d_in[4];
  const float* b_ai  = (const float*)d_in[5];
  const float* W_a   = (const float*)d_in[6];
  const float* b_a   = (const float*)d_in[7];
  const float* Wih_e = (const float*)d_in[8];
  const float* Whh_e = (const float*)d_in[9];
  const float* bih_e = (const float*)d_in[10];
  const float* bhh_e = (const float*)d_in[11];
  const float* W_d1  = (const float*)d_in[12];
  const float* b_d1  = (const float*)d_in[13];
  const float* W_d2  = (const float*)d_in[14];
  const float* b_d2  = (const float*)d_in[15];
  const float* W_fc  = (const float*)d_in[16];
  const float* b_fc  = (const float*)d_in[17];
  const float* Wih_d = (const float*)d_in[18];
  const float* Whh_d = (const float*)d_in[19];
  const float* bih_d = (const float*)d_in[20];
  const float* bhh_d = (const float*)d_in[21];
  const float* W_ff  = (const float*)d_in[22];
  const float* b_ff  = (const float*)d_in[23];
  float* ws  = (float*)d_ws;
  float* out = (float*)d_out;

  k_prep<<<256, 512, 0, stream>>>(W_ah, Wih_e, Whh_e, W_d1, Wih_d, Whh_d, ws);
  k_attn<<<512, 128, 0, stream>>>(x, W_ai, b_ai, ws);
  k_encoder<<<256, 1024, 0, stream>>>(x, b_ah, W_a, b_a, bih_e, bhh_e, ws);
  k_encw<<<1024, 256, 0, stream>>>(W_fc, ws);
  k_encproj<<<8192, 256, 0, stream>>>(W_d1, ws);
  k_decoder<<<512, 512, 0, stream>>>(y_h, b_d1, W_d2, b_d2, W_fc, b_fc,
                                     Wih_d, bih_d, bhh_d, W_ff, b_ff, ws, out);
}

// Round 11
// 13816.374 us; speedup vs baseline: 1.2591x; 1.2591x over previous
//
#include <hip/hip_runtime.h>
#include <hip/hip_bf16.h>
#include <hip/hip_fp16.h>

#define BB  512
#define TT  256
#define MM  81
#define HEE 256

// ---- workspace layout (float offsets) ----
#define OFF_W2AH   0          // half2[256 k2][256 j]  encoder p1 weight pairs
#define OFF_WE8    65536      // uint4[169 k2][256 j]  encoder LSTM, gate-major pairs
#define OFF_W8D1   238592     // uint4[64 k8][256 j]   decoder p1, 8 halves k=8k8..8k8+7
#define OFF_WD8    304128     // uint4[128 k2][256 j]  decoder Whh, gate-major pairs
#define OFF_ATTN   436224     // [512][81] attn_in
#define OFF_ENCW   477696     // [512][256] enc . W_fc[:256]
#define OFF_ENC    608768     // [512][256][256] input_encoded fp32
#define OFF_EPI    34163200   // half[512 b][256 t'][256 h] enc_proj
#define WS_FLOATS  50940416

typedef _Float16 hh2 __attribute__((ext_vector_type(2)));

__device__ __forceinline__ float frcp(float x) { return __builtin_amdgcn_rcpf(x); }
__device__ __forceinline__ float fsig(float x) { return frcp(1.f + __expf(-x)); }
__device__ __forceinline__ float ftanh(float x) { return 1.f - 2.f * frcp(__expf(2.f * x) + 1.f); }
__device__ __forceinline__ hh2 uash2(unsigned int u) { union { unsigned int u; hh2 h; } x; x.u = u; return x.h; }
__device__ __forceinline__ float fdot2f(unsigned int a, unsigned int b, float c) {
#if __has_builtin(__builtin_amdgcn_fdot2)
  return __builtin_amdgcn_fdot2(uash2(a), uash2(b), c, false);
#else
  hh2 ha = uash2(a), hb = uash2(b);
  return c + (float)ha.x * (float)hb.x + (float)ha.y * (float)hb.y;
#endif
}
__device__ __forceinline__ ushort f2h(float x) { return __half_as_ushort(__float2half(x)); }
__device__ __forceinline__ unsigned int pkh2(float a, float b) {
  __half2 h = __floats2half2_rn(a, b);
  return *(unsigned int*)&h;
}

// ---------------- weight prep ----------------
__global__ void k_prep(const float* __restrict__ W_ah, const float* __restrict__ Wih_e,
                       const float* __restrict__ Whh_e, const float* __restrict__ W_d1,
                       const float* __restrict__ Wih_d, const float* __restrict__ Whh_d,
                       float* __restrict__ ws) {
  int idx = blockIdx.x * 512 + threadIdx.x;
  if (idx < 65536) {  // encoder p1 pairs
    int k2 = idx >> 8, j = idx & 255;
    ((__half2*)(ws + OFF_W2AH))[idx] =
        __floats2half2_rn(W_ah[j * 512 + 2 * k2], W_ah[j * 512 + 2 * k2 + 1]);
  }
  if (idx < 16384) {  // decoder p1: uint4[64 k8][256 j]
    int k8 = idx >> 8, j = idx & 255;
    const float* wr = W_d1 + (size_t)j * 768 + 8 * k8;
    union { __half2 h[4]; uint4 u; } w;
    w.h[0] = __floats2half2_rn(wr[0], wr[1]);
    w.h[1] = __floats2half2_rn(wr[2], wr[3]);
    w.h[2] = __floats2half2_rn(wr[4], wr[5]);
    w.h[3] = __floats2half2_rn(wr[6], wr[7]);
    ((uint4*)(ws + OFF_W8D1))[idx] = w.u;
  }
  if (idx < 43264) {  // encoder LSTM: gate-major pairs over u=[wi(81);h(256);pad]
    int k2 = idx >> 8, j = idx & 255;
    auto we = [&](int g, int kk) -> float {
      if (kk < 81)  return Wih_e[(g * 256 + j) * 81 + kk];
      if (kk < 337) return Whh_e[(g * 256 + j) * 256 + (kk - 81)];
      return 0.f;
    };
    int ke = 2 * k2, ko = 2 * k2 + 1;
    union { __half2 h[4]; uint4 u; } w;
    w.h[0] = __floats2half2_rn(we(0, ke), we(0, ko));
    w.h[1] = __floats2half2_rn(we(1, ke), we(1, ko));
    w.h[2] = __floats2half2_rn(we(2, ke), we(2, ko));
    w.h[3] = __floats2half2_rn(we(3, ke), we(3, ko));
    ((uint4*)(ws + OFF_WE8))[idx] = w.u;
  }
  if (idx < 32768) {  // decoder Whh: gate-major pairs, 128 k2
    int k2 = idx >> 8, j = idx & 255;
    int ke = 2 * k2, ko = 2 * k2 + 1;
    union { __half2 h[4]; uint4 u; } w;
    w.h[0] = __floats2half2_rn(Whh_d[(0 * 256 + j) * 256 + ke], Whh_d[(0 * 256 + j) * 256 + ko]);
    w.h[1] = __floats2half2_rn(Whh_d[(1 * 256 + j) * 256 + ke], Whh_d[(1 * 256 + j) * 256 + ko]);
    w.h[2] = __floats2half2_rn(Whh_d[(2 * 256 + j) * 256 + ke], Whh_d[(2 * 256 + j) * 256 + ko]);
    w.h[3] = __floats2half2_rn(Whh_d[(3 * 256 + j) * 256 + ke], Whh_d[(3 * 256 + j) * 256 + ko]);
    ((uint4*)(ws + OFF_WD8))[idx] = w.u;
  }
}

// ---------------- attn_in[b][m] ----------------
__global__ void k_attn(const float* __restrict__ x, const float* __restrict__ W_ai,
                       const float* __restrict__ b_ai, float* __restrict__ ws) {
  __shared__ float wai[256];
  const int b = blockIdx.x, tid = threadIdx.x;  // 128 threads
  wai[tid] = W_ai[tid];
  wai[128 + tid] = W_ai[128 + tid];
  __syncthreads();
  if (tid < MM) {
    float acc = b_ai[0];
    const float* xp = x + (size_t)b * TT * MM + tid;
    #pragma unroll 8
    for (int t = 0; t < TT; ++t) acc = fmaf(xp[t * MM], wai[t], acc);
    ws[OFF_ATTN + b * MM + tid] = acc;
  }
}

// ---------------- encoder: unchanged from R8 ----------------
__global__ __launch_bounds__(1024, 2) void k_encoder(
    const float* __restrict__ x, const float* __restrict__ b_ah,
    const float* __restrict__ W_a, const float* __restrict__ b_a,
    const float* __restrict__ bih_e, const float* __restrict__ bhh_e,
    float* __restrict__ ws) {
  __shared__ __align__(16) float aA[2048];
  __shared__ __align__(16) float4 gA[2048];
  __shared__ __align__(16) float hpb[512];
  __shared__ __align__(16) float wa2[256];
  __shared__ __align__(16) ushort hcb[2][512];
  __shared__ __align__(16) ushort uu[2][344];
  const int tid = threadIdx.x;
  const int j = tid & 255, q = tid >> 8;
  const int b0 = blockIdx.x * 2, b1 = b0 + 1;

  if (tid < 256) wa2[tid] = W_a[tid];
  if (tid < 512) { hcb[0][tid] = 0; hcb[1][tid] = 0; }
  if (tid < 344) { uu[0][tid] = 0; uu[1][tid] = 0; }
  float bahr = 0.f; float4 bias4 = {0, 0, 0, 0};
  if (tid < 512) {
    bahr = b_ah[j];
    bias4.x = bih_e[j] + bhh_e[j];
    bias4.y = bih_e[256 + j] + bhh_e[256 + j];
    bias4.z = bih_e[512 + j] + bhh_e[512 + j];
    bias4.w = bih_e[768 + j] + bhh_e[768 + j];
  }
  float ai0 = 0.f, ai1 = 0.f;
  {
    int m = tid & 127;
    if (m < MM) {
      ai0 = ws[OFF_ATTN + b0 * MM + m];
      ai1 = ws[OFF_ATTN + b1 * MM + m];
    }
  }
  const float bav = b_a[0];
  float xc0 = 0.f, xc1 = 0.f;
  if (tid < 128) {
    int bb = (tid >= 64) ? b1 : b0;
    int lane = tid & 63;
    xc0 = x[((size_t)bb * TT) * MM + lane];
    xc1 = (lane < 17) ? x[((size_t)bb * TT) * MM + 64 + lane] : 0.f;
  }
  const unsigned int* __restrict__ Wah2u = (const unsigned int*)(ws + OFF_W2AH);
  const uint4* __restrict__ We8 = (const uint4*)(ws + OFF_WE8);
  const unsigned int* __restrict__ hc0 = (const unsigned int*)hcb[0];
  const unsigned int* __restrict__ hc1 = (const unsigned int*)hcb[1];
  const unsigned int* __restrict__ u0p = (const unsigned int*)uu[0];
  const unsigned int* __restrict__ u1p = (const unsigned int*)uu[1];
  float creg = 0.f;
  __syncthreads();

  for (int t = 0; t < TT; ++t) {
    {
      float a0 = 0.f, a1 = 0.f;
      const int kb = q * 64;
      #pragma unroll 8
      for (int i = 0; i < 64; ++i) {
        unsigned int w = Wah2u[(kb + i) * 256 + j];
        a0 = fdot2f(w, hc0[kb + i], a0);
        a1 = fdot2f(w, hc1[kb + i], a1);
      }
      aA[(q * 256 + j) * 2 + 0] = a0;
      aA[(q * 256 + j) * 2 + 1] = a1;
      float4 g0 = {0, 0, 0, 0}, g1 = {0, 0, 0, 0};
      const int ku0 = 41 + q * 32;
      #pragma unroll 4
      for (int i = 0; i < 32; ++i) {
        int ku = ku0 + i;
        uint4 wu = We8[ku * 256 + j];
        unsigned int ua = u0p[ku], ub = u1p[ku];
        g0.x = fdot2f(wu.x, ua, g0.x); g0.y = fdot2f(wu.y, ua, g0.y);
        g0.z = fdot2f(wu.z, ua, g0.z); g0.w = fdot2f(wu.w, ua, g0.w);
        g1.x = fdot2f(wu.x, ub, g1.x); g1.y = fdot2f(wu.y, ub, g1.y);
        g1.z = fdot2f(wu.z, ub, g1.z); g1.w = fdot2f(wu.w, ub, g1.w);
      }
      gA[(q * 2 + 0) * 256 + j] = g0;
      gA[(q * 2 + 1) * 256 + j] = g1;
    }
    __syncthreads();
    if (tid < 512) {
      int b = tid >> 8, h = tid & 255;
      hpb[2 * h + b] = aA[(0 * 256 + h) * 2 + b] + aA[(1 * 256 + h) * 2 + b] +
                       aA[(2 * 256 + h) * 2 + b] + aA[(3 * 256 + h) * 2 + b] + bahr;
    }
    __syncthreads();
    {
      int m = tid & 127, tq = tid >> 7;
      if (m < MM) {
        float e0 = 0.f, e1 = 0.f;
        #pragma unroll 8
        for (int i = tq * 16; i < tq * 16 + 16; ++i) {
          float4 hv = *(const float4*)&hpb[i * 4];
          float2 wv = *(const float2*)&wa2[i * 2];
          e0 += ftanh(hv.x + ai0) * wv.x + ftanh(hv.z + ai0) * wv.y;
          e1 += ftanh(hv.y + ai1) * wv.x + ftanh(hv.w + ai1) * wv.y;
        }
        aA[(tq * 2 + 0) * 96 + m] = e0;
        aA[(tq * 2 + 1) * 96 + m] = e1;
      }
    }
    __syncthreads();
    if (tid < 128) {
      int wv_id = tid >> 6, lane = tid & 63;
      float v0 = bav, v1 = bav;
      #pragma unroll
      for (int tq = 0; tq < 8; ++tq) {
        v0 += aA[(tq * 2 + wv_id) * 96 + lane];
        if (lane < 17) v1 += aA[(tq * 2 + wv_id) * 96 + 64 + lane];
      }
      float e0 = __expf(v0);
      float e1 = (lane < 17) ? __expf(v1) : 0.f;
      float sm = e0 + e1;
      #pragma unroll
      for (int d = 1; d < 64; d <<= 1) sm += __shfl_xor(sm, d);
      float inv = frcp(sm);
      uu[wv_id][lane] = f2h(e0 * inv * xc0);
      if (lane < 17) uu[wv_id][64 + lane] = f2h(e1 * inv * xc1);
      if (t < 255) {
        int bb = wv_id ? b1 : b0;
        xc0 = x[((size_t)bb * TT + t + 1) * MM + lane];
        xc1 = (lane < 17) ? x[((size_t)bb * TT + t + 1) * MM + 64 + lane] : 0.f;
      }
    }
    __syncthreads();
    {
      const int kA = (q == 0) ? 0 : (q == 1) ? 11 : (q == 2) ? 21 : 31;
      const int kB = (q == 0) ? 11 : (q == 1) ? 21 : (q == 2) ? 31 : 41;
      float4 g0 = gA[(q * 2 + 0) * 256 + j];
      float4 g1 = gA[(q * 2 + 1) * 256 + j];
      for (int ku = kA; ku < kB; ++ku) {
        uint4 wu = We8[ku * 256 + j];
        unsigned int ua = u0p[ku], ub = u1p[ku];
        g0.x = fdot2f(wu.x, ua, g0.x); g0.y = fdot2f(wu.y, ua, g0.y);
        g0.z = fdot2f(wu.z, ua, g0.z); g0.w = fdot2f(wu.w, ua, g0.w);
        g1.x = fdot2f(wu.x, ub, g1.x); g1.y = fdot2f(wu.y, ub, g1.y);
        g1.z = fdot2f(wu.z, ub, g1.z); g1.w = fdot2f(wu.w, ub, g1.w);
      }
      gA[(q * 2 + 0) * 256 + j] = g0;
      gA[(q * 2 + 1) * 256 + j] = g1;
    }
    __syncthreads();
    if (tid < 512) {
      int b = tid >> 8, jj = tid & 255;
      float4 s0 = gA[(0 * 2 + b) * 256 + jj];
      float4 s1 = gA[(1 * 2 + b) * 256 + jj];
      float4 s2 = gA[(2 * 2 + b) * 256 + jj];
      float4 s3 = gA[(3 * 2 + b) * 256 + jj];
      float gi = s0.x + s1.x + s2.x + s3.x + bias4.x;
      float gf = s0.y + s1.y + s2.y + s3.y + bias4.y;
      float gg = s0.z + s1.z + s2.z + s3.z + bias4.z;
      float go = s0.w + s1.w + s2.w + s3.w + bias4.w;
      float c = fsig(gf) * creg + fsig(gi) * ftanh(gg);
      float h = fsig(go) * ftanh(c);
      creg = c;
      hcb[b][jj] = f2h(h);
      hcb[b][256 + jj] = f2h(c);
      uu[b][81 + jj] = f2h(h);
      ws[OFF_ENC + (((size_t)(b ? b1 : b0) * TT + t) * HEE + jj)] = h;
    }
    __syncthreads();
  }
}

// ---------------- encW[b][t] = enc[b,t,:] . W_fc[:256] ----------------
__global__ __launch_bounds__(256) void k_encw(const float* __restrict__ W_fc, float* __restrict__ ws) {
  const float* __restrict__ enc = ws + OFF_ENC;
  const int wv = threadIdx.x >> 6, lane = threadIdx.x & 63;
  float4 wfc = reinterpret_cast<const float4*>(W_fc)[lane];
  for (int r = blockIdx.x * 4 + wv; r < BB * TT; r += 4096) {
    float4 e = reinterpret_cast<const float4*>(enc + (size_t)r * HEE)[lane];
    float d = e.x * wfc.x + e.y * wfc.y + e.z * wfc.z + e.w * wfc.w;
    #pragma unroll
    for (int dd = 1; dd < 64; dd <<= 1) d += __shfl_xor(d, dd);
    if (lane == 0) ws[OFF_ENCW + r] = d;
  }
}

// ---------------- enc_proj fp16: epH[b][t'][h] ----------------
__global__ __launch_bounds__(256) void k_encproj(const float* __restrict__ W_d1, float* __restrict__ ws) {
  __shared__ __align__(16) float le[16][256];
  const int tid = threadIdx.x;
  const int b = blockIdx.x >> 4;
  const int t0 = (blockIdx.x & 15) * 16;
  const float* __restrict__ enc = ws + OFF_ENC;
  __half* __restrict__ epH = (__half*)(ws + OFF_EPI);
  #pragma unroll
  for (int rr = 0; rr < 16; ++rr)
    le[rr][tid] = enc[((size_t)b * TT + (t0 + rr)) * HEE + tid];
  __syncthreads();
  const float4* wrow = (const float4*)(W_d1 + (size_t)tid * 768 + 512);
  float acc[16];
  #pragma unroll
  for (int r = 0; r < 16; ++r) acc[r] = 0.f;
  for (int e4 = 0; e4 < 64; ++e4) {
    float4 w = wrow[e4];
    #pragma unroll
    for (int r = 0; r < 16; ++r) {
      float4 ev = *(const float4*)&le[r][e4 * 4];
      acc[r] += ev.x * w.x + ev.y * w.y + ev.z * w.z + ev.w * w.w;
    }
  }
  #pragma unroll
  for (int rr = 0; rr < 16; ++rr)
    epH[((size_t)b * TT + (t0 + rr)) * HEE + tid] = __float2half(acc[rr]);
}

// ---------------- decoder: 1024 threads, 2 batches per step, 255 steps ----------------
// b0 ep in swizzled LDS; b1 ep streamed from global (L2-resident) each step.
__global__ __launch_bounds__(1024) void k_decoder(
    const float* __restrict__ y_history, const float* __restrict__ b_d1,
    const float* __restrict__ W_d2, const float* __restrict__ b_d2,
    const float* __restrict__ W_fc, const float* __restrict__ b_fc,
    const float* __restrict__ Wih_d,
    const float* __restrict__ bih_d, const float* __restrict__ bhh_d,
    const float* __restrict__ W_ff, const float* __restrict__ b_ff,
    float* __restrict__ ws, float* __restrict__ out) {
  __shared__ __align__(16) ushort epL[65536];   // b0 enc_proj, swizzled (128 KB)
  __shared__ __align__(16) float aA[2048];      // p1/score/ctx partials (q*256+tp)*2+b (8 KB)
  __shared__ __align__(16) uint2 gAh[2048];     // fp16 gate partials [(q*2+b)*256+j] (16 KB)
  __shared__ __align__(16) float ddp2[512];     // d packed 2h+b; awls at finale (2 KB)
  __shared__ __align__(16) ushort hcb[2][512];  // fp16 [h;c] per batch (2 KB)
  __shared__ __align__(16) float w2f[256];      // W_d2 fp32 (1 KB)
  __shared__ __align__(16) float ybuf[512];     // y*wfcy+bfc, 2s+b (2 KB)
  __shared__ float red[2][8];
  const int tid = threadIdx.x;
  const int tp = tid & 255, q = tid >> 8;
  const int lane = tid & 63, wvid = tid >> 6;
  const int b0 = blockIdx.x * 2, b1 = b0 + 1;
  const float wfcy = W_fc[256], bfc = b_fc[0], bd2v = b_d2[0], bffv = b_ff[0];

  if (tid < 256) w2f[tid] = W_d2[tid];
  ((ushort*)hcb)[tid] = 0;
  if (tid < 510) {
    int s = tid >> 1, b = tid & 1;
    ybuf[tid] = y_history[(size_t)(b ? b1 : b0) * 255 + s] * wfcy + bfc;
  }
  const float bd1q = 0.25f * b_d1[tp];
  float4 biasd, wy;
  biasd.x = bih_d[tp] + bhh_d[tp];
  biasd.y = bih_d[256 + tp] + bhh_d[256 + tp];
  biasd.z = bih_d[512 + tp] + bhh_d[512 + tp];
  biasd.w = bih_d[768 + tp] + bhh_d[768 + tp];
  wy.x = Wih_d[tp]; wy.y = Wih_d[256 + tp]; wy.z = Wih_d[512 + tp]; wy.w = Wih_d[768 + tp];
  const float wffh = W_ff[tp], wffc = W_ff[256 + tp];
  const float ewr = ws[OFF_ENCW + (size_t)((q & 1) ? b1 : b0) * 256 + tp];

  const uint4* __restrict__ W8 = (const uint4*)(ws + OFF_W8D1);
  const uint4* __restrict__ Wd8 = (const uint4*)(ws + OFF_WD8);
  const uint4* __restrict__ epg = (const uint4*)(ws + OFF_EPI);
  const uint4* __restrict__ ep16 = (const uint4*)epL;
  const uint4* __restrict__ hc4_0 = (const uint4*)hcb[0];
  const uint4* __restrict__ hc4_1 = (const uint4*)hcb[1];
  const unsigned int* __restrict__ hc0u = (const unsigned int*)hcb[0];
  const unsigned int* __restrict__ hc1u = (const unsigned int*)hcb[1];

  // b0 ep -> swizzled LDS (proven R8 pattern)
  {
    const uint4* src = epg + (size_t)b0 * 8192;
    #pragma unroll
    for (int k = 0; k < 8; ++k) {
      int g = k * 1024 + tid;
      int t = g >> 5, c = g & 31;
      ((uint4*)epL)[(g & ~31) | (c ^ (t & 31))] = src[g];
    }
  }
  const uint4* __restrict__ ep1g = epg + (size_t)b1 * 8192 + tp * 32 + q * 8;
  __syncthreads();

  float hreg = 0.f, creg = 0.f;
  float escls = 0.f, invls = 0.f, esc = 0.f;

  for (int s = 0; s < 255; ++s) {
    // ---- A: p1 partials (shared weights, both batches) + Whh gate partials ----
    {
      float a0 = bd1q, a1 = bd1q;
      const int k8b = q * 16;
      #pragma unroll 4
      for (int i = 0; i < 16; ++i) {
        int k8 = k8b + i;
        uint4 wu = W8[k8 * 256 + tp];
        uint4 h0 = hc4_0[k8], h1 = hc4_1[k8];
        a0 = fdot2f(wu.x, h0.x, a0); a0 = fdot2f(wu.y, h0.y, a0);
        a0 = fdot2f(wu.z, h0.z, a0); a0 = fdot2f(wu.w, h0.w, a0);
        a1 = fdot2f(wu.x, h1.x, a1); a1 = fdot2f(wu.y, h1.y, a1);
        a1 = fdot2f(wu.z, h1.z, a1); a1 = fdot2f(wu.w, h1.w, a1);
      }
      *(float2*)&aA[(q * 256 + tp) * 2] = make_float2(a0, a1);
      float4 g0 = {0, 0, 0, 0}, g1 = {0, 0, 0, 0};
      const int k2b = q * 32;
      #pragma unroll 4
      for (int i = 0; i < 32; ++i) {
        int k2 = k2b + i;
        uint4 wu = Wd8[k2 * 256 + tp];
        unsigned int u0 = hc0u[k2], u1 = hc1u[k2];
        g0.x = fdot2f(wu.x, u0, g0.x); g0.y = fdot2f(wu.y, u0, g0.y);
        g0.z = fdot2f(wu.z, u0, g0.z); g0.w = fdot2f(wu.w, u0, g0.w);
        g1.x = fdot2f(wu.x, u1, g1.x); g1.y = fdot2f(wu.y, u1, g1.y);
        g1.z = fdot2f(wu.z, u1, g1.z); g1.w = fdot2f(wu.w, u1, g1.w);
      }
      uint2 p0, p1;
      p0.x = pkh2(g0.x, g0.y); p0.y = pkh2(g0.z, g0.w);
      p1.x = pkh2(g1.x, g1.y); p1.y = pkh2(g1.z, g1.w);
      gAh[(q * 2 + 0) * 256 + tp] = p0;
      gAh[(q * 2 + 1) * 256 + tp] = p1;
    }
    __syncthreads();
    // ---- B: d combine ----
    if (tid < 512) {
      int b = tid >> 8, h = tid & 255;
      ddp2[2 * h + b] = aA[(0 * 256 + h) * 2 + b] + aA[(1 * 256 + h) * 2 + b] +
                        aA[(2 * 256 + h) * 2 + b] + aA[(3 * 256 + h) * 2 + b];
    }
    __syncthreads();
    // ---- C: score partials (b0 from LDS, b1 from global w/ 1-ahead prefetch) ----
    {
      float q0 = 0.f, q1 = 0.f;
      const int rowbase = tp * 32, sw = tp & 31;
      uint4 eN = ep1g[0];
      #pragma unroll
      for (int k = 0; k < 8; ++k) {
        uint4 e1u = eN;
        if (k < 7) eN = ep1g[k + 1];
        uint4 e0u = ep16[rowbase + ((q * 8 + k) ^ sw)];
        const int h8 = q * 64 + k * 8;
        const __half2* e0h = (const __half2*)&e0u;
        const __half2* e1h = (const __half2*)&e1u;
        #pragma unroll
        for (int jj = 0; jj < 4; ++jj) {
          float2 ea = __half22float2(e0h[jj]);
          float2 eb = __half22float2(e1h[jj]);
          float2 wf = *(const float2*)&w2f[h8 + 2 * jj];
          float4 dv = *(const float4*)&ddp2[2 * (h8 + 2 * jj)];
          q0 += wf.x * ftanh(ea.x + dv.x) + wf.y * ftanh(ea.y + dv.z);
          q1 += wf.x * ftanh(eb.x + dv.y) + wf.y * ftanh(eb.y + dv.w);
        }
      }
      *(float2*)&aA[(q * 256 + tp) * 2] = make_float2(q0, q1);
    }
    __syncthreads();
    // ---- D: softmax partial reductions (q<2 -> batch q; no max-shift) ----
    if (q < 2) {
      float v = aA[(0 * 256 + tp) * 2 + q] + aA[(1 * 256 + tp) * 2 + q] +
                aA[(2 * 256 + tp) * 2 + q] + aA[(3 * 256 + tp) * 2 + q] + bd2v;
      esc = __expf(v);
      float den = esc, num = esc * ewr;
      #pragma unroll
      for (int d = 1; d < 64; d <<= 1) { den += __shfl_xor(den, d); num += __shfl_xor(num, d); }
      if (lane == 0) { red[0][wvid] = den; red[1][wvid] = num; }
    }
    __syncthreads();
    // ---- E: y + gate combine + state update (tid<512, b=tid>>8) ----
    if (tid < 512) {
      int b = tid >> 8, j = tid & 255;
      float den = red[0][b * 4 + 0] + red[0][b * 4 + 1] + red[0][b * 4 + 2] + red[0][b * 4 + 3];
      float num = red[1][b * 4 + 0] + red[1][b * 4 + 1] + red[1][b * 4 + 2] + red[1][b * 4 + 3];
      float inv = frcp(den);
      float y = num * inv + ybuf[2 * s + b];
      if (s == 254) { escls = esc; invls = inv; }
      float gi = wy.x * y + biasd.x, gf = wy.y * y + biasd.y;
      float gg = wy.z * y + biasd.z, go = wy.w * y + biasd.w;
      #pragma unroll
      for (int qq = 0; qq < 4; ++qq) {
        uint2 p = gAh[(qq * 2 + b) * 256 + j];
        float2 lo = __half22float2(*(__half2*)&p.x);
        float2 hi = __half22float2(*(__half2*)&p.y);
        gi += lo.x; gf += lo.y; gg += hi.x; go += hi.y;
      }
      float c = fsig(gf) * creg + fsig(gi) * ftanh(gg);
      float h = fsig(go) * ftanh(c);
      creg = c; hreg = h;
      hcb[b][j] = f2h(h);
      hcb[b][256 + j] = f2h(c);
    }
    __syncthreads();
  }

  // ---- finale: last-step aw (into ddp2) + ctx + output ----
  if (tid < 512) ddp2[2 * tp + (tid >> 8)] = escls * invls;
  __syncthreads();
  {
    float c0 = 0.f, c1 = 0.f;
    const float* __restrict__ e0p = ws + OFF_ENC + (size_t)b0 * TT * HEE;
    const float* __restrict__ e1p = ws + OFF_ENC + (size_t)b1 * TT * HEE;
    for (int t = q * 64; t < q * 64 + 64; ++t) {
      float2 aw = *(const float2*)&ddp2[2 * t];
      c0 = fmaf(aw.x, e0p[(size_t)t * HEE + tp], c0);
      c1 = fmaf(aw.y, e1p[(size_t)t * HEE + tp], c1);
    }
    __syncthreads();
    *(float2*)&aA[(q * 256 + tp) * 2] = make_float2(c0, c1);
  }
  __syncthreads();
  if (tid < 512) {
    int b = tid >> 8, h = tid & 255;
    float ctx = aA[(0 * 256 + h) * 2 + b] + aA[(1 * 256 + h) * 2 + b] +
                aA[(2 * 256 + h) * 2 + b] + aA[(3 * 256 + h) * 2 + b];
    float p = hreg * wffh + ctx * wffc;
    #pragma unroll
    for (int d = 1; d < 64; d <<= 1) p += __shfl_xor(p, d);
    if (lane == 0) red[0][wvid] = p;
  }
  __syncthreads();
  if (tid == 0)   out[b0] = red[0][0] + red[0][1] + red[0][2] + red[0][3] + bffv;
  if (tid == 256) out[b1] = red[0][4] + red[0][5] + red[0][6] + red[0][7] + bffv;
}

extern "C" void kernel_launch(void* const* d_in, const int* in_sizes, int n_in,
                              void* d_out, int out_size, void* d_ws, size_t ws_size,
                              hipStream_t stream) {
  if (ws_size < (size_t)WS_FLOATS * sizeof(float)) return;
  const float* x     = (const float*)d_in[0];
  const float* y_h   = (const float*)d_in[1];
  const float* W_ah  = (const float*)d_in[2];
  const float* b_ah  = (const float*)d_in[3];
  const float* W_ai  = (const float*)d_in[4];
  const float* b_ai  = (const float*)d_in[5];
  const float* W_a   = (const float*)d_in[6];
  const float* b_a   = (const float*)d_in[7];
  const float* Wih_e = (const float*)d_in[8];
  const float* Whh_e = (const float*)d_in[9];
  const float* bih_e = (const float*)d_in[10];
  const float* bhh_e = (const float*)d_in[11];
  const float* W_d1  = (const float*)d_in[12];
  const float* b_d1  = (const float*)d_in[13];
  const float* W_d2  = (const float*)d_in[14];
  const float* b_d2  = (const float*)d_in[15];
  const float* W_fc  = (const float*)d_in[16];
  const float* b_fc  = (const float*)d_in[17];
  const float* Wih_d = (const float*)d_in[18];
  const float* Whh_d = (const float*)d_in[19];
  const float* bih_d = (const float*)d_in[20];
  const float* bhh_d = (const float*)d_in[21];
  const float* W_ff  = (const float*)d_in[22];
  const float* b_ff  = (const float*)d_in[23];
  float* ws  = (float*)d_ws;
  float* out = (float*)d_out;

  k_prep<<<256, 512, 0, stream>>>(W_ah, Wih_e, Whh_e, W_d1, Wih_d, Whh_d, ws);
  k_attn<<<512, 128, 0, stream>>>(x, W_ai, b_ai, ws);
  k_encoder<<<256, 1024, 0, stream>>>(x, b_ah, W_a, b_a, bih_e, bhh_e, ws);
  k_encw<<<1024, 256, 0, stream>>>(W_fc, ws);
  k_encproj<<<8192, 256, 0, stream>>>(W_d1, ws);
  k_decoder<<<256, 1024, 0, stream>>>(y_h, b_d1, W_d2, b_d2, W_fc, b_fc,
                                      Wih_d, bih_d, bhh_d, W_ff, b_ff, ws, out);
}

// Round 12
// 11083.488 us; speedup vs baseline: 1.5696x; 1.2466x over previous
//
#include <hip/hip_runtime.h>
#include <hip/hip_bf16.h>
#include <hip/hip_fp16.h>

#define BB  512
#define TT  256
#define MM  81
#define HEE 256

// ---- workspace layout (float offsets) ----
#define OFF_W2AH   0          // half2[256 k2][256 j]  encoder p1 weight pairs
#define OFF_WE8    65536      // uint4[169 k2][256 j]  encoder LSTM, gate-major pairs
#define OFF_W8D1   238592     // uint4[64 k8][256 j]   decoder p1, 8 halves
#define OFF_WD8    304128     // uint4[128 k2][256 j]  decoder Whh, gate-major pairs
#define OFF_ATTN   436224     // [512][81] attn_in
#define OFF_ENCW   477696     // [512][256] enc . W_fc[:256]
#define OFF_ENC    608768     // [512][256][256] input_encoded fp32
#define OFF_EPI    34163200   // half[512 b][256 t'][256 h] enc_proj (fp16 master)
#define WS_FLOATS  50940416

typedef _Float16 hh2 __attribute__((ext_vector_type(2)));

__device__ __forceinline__ float frcp(float x) { return __builtin_amdgcn_rcpf(x); }
__device__ __forceinline__ float fsig(float x) { return frcp(1.f + __expf(-x)); }
__device__ __forceinline__ float ftanh(float x) { return 1.f - 2.f * frcp(__expf(2.f * x) + 1.f); }
__device__ __forceinline__ hh2 uash2(unsigned int u) { union { unsigned int u; hh2 h; } x; x.u = u; return x.h; }
__device__ __forceinline__ float fdot2f(unsigned int a, unsigned int b, float c) {
#if __has_builtin(__builtin_amdgcn_fdot2)
  return __builtin_amdgcn_fdot2(uash2(a), uash2(b), c, false);
#else
  hh2 ha = uash2(a), hb = uash2(b);
  return c + (float)ha.x * (float)hb.x + (float)ha.y * (float)hb.y;
#endif
}
__device__ __forceinline__ ushort f2h(float x) { return __half_as_ushort(__float2half(x)); }
__device__ __forceinline__ unsigned int pkh2(float a, float b) {
  __half2 h = __floats2half2_rn(a, b);
  return *(unsigned int*)&h;
}

// ---- fp8 e4m3 helpers (HW builtins; self-consistent SW fallback) ----
#if __has_builtin(__builtin_amdgcn_cvt_pk_f32_fp8) && __has_builtin(__builtin_amdgcn_cvt_pk_fp8_f32)
typedef float ff2 __attribute__((ext_vector_type(2)));
__device__ __forceinline__ float2 cvt2lo(unsigned v) { ff2 r = __builtin_amdgcn_cvt_pk_f32_fp8(v, false); return make_float2(r[0], r[1]); }
__device__ __forceinline__ float2 cvt2hi(unsigned v) { ff2 r = __builtin_amdgcn_cvt_pk_f32_fp8(v, true);  return make_float2(r[0], r[1]); }
__device__ __forceinline__ unsigned pk4_fp8(unsigned a, unsigned b) {
  float2 fa = __half22float2(*(__half2*)&a);
  float2 fb = __half22float2(*(__half2*)&b);
  int r = __builtin_amdgcn_cvt_pk_fp8_f32(fa.x, fa.y, 0, false);
  r = __builtin_amdgcn_cvt_pk_fp8_f32(fb.x, fb.y, r, true);
  return (unsigned)r;
}
#else
__device__ __forceinline__ float dec1_fp8(unsigned b) {
  unsigned s = b >> 7, ef = (b >> 3) & 0xf, m = b & 7;
  float v = (ef == 0) ? (float)m * 0.001953125f
                      : (1.f + (float)m * 0.125f) * exp2f((float)((int)ef - 7));
  return s ? -v : v;
}
__device__ __forceinline__ float2 cvt2lo(unsigned v) { return make_float2(dec1_fp8(v & 0xff), dec1_fp8((v >> 8) & 0xff)); }
__device__ __forceinline__ float2 cvt2hi(unsigned v) { return make_float2(dec1_fp8((v >> 16) & 0xff), dec1_fp8((v >> 24) & 0xff)); }
__device__ __forceinline__ unsigned enc1_fp8(float x) {
  unsigned u = __float_as_uint(x); unsigned sgn = (u >> 31) << 7;
  float ax = fabsf(x);
  if (ax < 0.0009765625f) return sgn;
  if (ax >= 448.f) return sgn | 0x7e;
  if (ax < 0.015625f) { int k = (int)rintf(ax * 512.f); return (k >= 8) ? (sgn | 0x08) : (sgn | (unsigned)k); }
  int e = (int)((u >> 23) & 0xff) - 127;
  unsigned m = u & 0x7fffff;
  unsigned mr = m + 0x7ffff + ((m >> 20) & 1);
  if (mr >= 0x800000) { mr = 0; ++e; if (e > 8) return sgn | 0x7e; }
  return sgn | (unsigned)((e + 7) << 3) | (mr >> 20);
}
__device__ __forceinline__ unsigned pk4_fp8(unsigned a, unsigned b) {
  float2 fa = __half22float2(*(__half2*)&a);
  float2 fb = __half22float2(*(__half2*)&b);
  return enc1_fp8(fa.x) | (enc1_fp8(fa.y) << 8) | (enc1_fp8(fb.x) << 16) | (enc1_fp8(fb.y) << 24);
}
#endif

// ---------------- weight prep ----------------
__global__ void k_prep(const float* __restrict__ W_ah, const float* __restrict__ Wih_e,
                       const float* __restrict__ Whh_e, const float* __restrict__ W_d1,
                       const float* __restrict__ Wih_d, const float* __restrict__ Whh_d,
                       float* __restrict__ ws) {
  int idx = blockIdx.x * 512 + threadIdx.x;
  if (idx < 65536) {  // encoder p1 pairs
    int k2 = idx >> 8, j = idx & 255;
    ((__half2*)(ws + OFF_W2AH))[idx] =
        __floats2half2_rn(W_ah[j * 512 + 2 * k2], W_ah[j * 512 + 2 * k2 + 1]);
  }
  if (idx < 16384) {  // decoder p1: uint4[64 k8][256 j]
    int k8 = idx >> 8, j = idx & 255;
    const float* wr = W_d1 + (size_t)j * 768 + 8 * k8;
    union { __half2 h[4]; uint4 u; } w;
    w.h[0] = __floats2half2_rn(wr[0], wr[1]);
    w.h[1] = __floats2half2_rn(wr[2], wr[3]);
    w.h[2] = __floats2half2_rn(wr[4], wr[5]);
    w.h[3] = __floats2half2_rn(wr[6], wr[7]);
    ((uint4*)(ws + OFF_W8D1))[idx] = w.u;
  }
  if (idx < 43264) {  // encoder LSTM: gate-major pairs over u=[wi(81);h(256);pad]
    int k2 = idx >> 8, j = idx & 255;
    auto we = [&](int g, int kk) -> float {
      if (kk < 81)  return Wih_e[(g * 256 + j) * 81 + kk];
      if (kk < 337) return Whh_e[(g * 256 + j) * 256 + (kk - 81)];
      return 0.f;
    };
    int ke = 2 * k2, ko = 2 * k2 + 1;
    union { __half2 h[4]; uint4 u; } w;
    w.h[0] = __floats2half2_rn(we(0, ke), we(0, ko));
    w.h[1] = __floats2half2_rn(we(1, ke), we(1, ko));
    w.h[2] = __floats2half2_rn(we(2, ke), we(2, ko));
    w.h[3] = __floats2half2_rn(we(3, ke), we(3, ko));
    ((uint4*)(ws + OFF_WE8))[idx] = w.u;
  }
  if (idx < 32768) {  // decoder Whh: gate-major pairs, 128 k2
    int k2 = idx >> 8, j = idx & 255;
    int ke = 2 * k2, ko = 2 * k2 + 1;
    union { __half2 h[4]; uint4 u; } w;
    w.h[0] = __floats2half2_rn(Whh_d[(0 * 256 + j) * 256 + ke], Whh_d[(0 * 256 + j) * 256 + ko]);
    w.h[1] = __floats2half2_rn(Whh_d[(1 * 256 + j) * 256 + ke], Whh_d[(1 * 256 + j) * 256 + ko]);
    w.h[2] = __floats2half2_rn(Whh_d[(2 * 256 + j) * 256 + ke], Whh_d[(2 * 256 + j) * 256 + ko]);
    w.h[3] = __floats2half2_rn(Whh_d[(3 * 256 + j) * 256 + ke], Whh_d[(3 * 256 + j) * 256 + ko]);
    ((uint4*)(ws + OFF_WD8))[idx] = w.u;
  }
}

// ---------------- attn_in[b][m] ----------------
__global__ void k_attn(const float* __restrict__ x, const float* __restrict__ W_ai,
                       const float* __restrict__ b_ai, float* __restrict__ ws) {
  __shared__ float wai[256];
  const int b = blockIdx.x, tid = threadIdx.x;  // 128 threads
  wai[tid] = W_ai[tid];
  wai[128 + tid] = W_ai[128 + tid];
  __syncthreads();
  if (tid < MM) {
    float acc = b_ai[0];
    const float* xp = x + (size_t)b * TT * MM + tid;
    #pragma unroll 8
    for (int t = 0; t < TT; ++t) acc = fmaf(xp[t * MM], wai[t], acc);
    ws[OFF_ATTN + b * MM + tid] = acc;
  }
}

// ---------------- encoder: unchanged from R8 ----------------
__global__ __launch_bounds__(1024, 2) void k_encoder(
    const float* __restrict__ x, const float* __restrict__ b_ah,
    const float* __restrict__ W_a, const float* __restrict__ b_a,
    const float* __restrict__ bih_e, const float* __restrict__ bhh_e,
    float* __restrict__ ws) {
  __shared__ __align__(16) float aA[2048];
  __shared__ __align__(16) float4 gA[2048];
  __shared__ __align__(16) float hpb[512];
  __shared__ __align__(16) float wa2[256];
  __shared__ __align__(16) ushort hcb[2][512];
  __shared__ __align__(16) ushort uu[2][344];
  const int tid = threadIdx.x;
  const int j = tid & 255, q = tid >> 8;
  const int b0 = blockIdx.x * 2, b1 = b0 + 1;

  if (tid < 256) wa2[tid] = W_a[tid];
  if (tid < 512) { hcb[0][tid] = 0; hcb[1][tid] = 0; }
  if (tid < 344) { uu[0][tid] = 0; uu[1][tid] = 0; }
  float bahr = 0.f; float4 bias4 = {0, 0, 0, 0};
  if (tid < 512) {
    bahr = b_ah[j];
    bias4.x = bih_e[j] + bhh_e[j];
    bias4.y = bih_e[256 + j] + bhh_e[256 + j];
    bias4.z = bih_e[512 + j] + bhh_e[512 + j];
    bias4.w = bih_e[768 + j] + bhh_e[768 + j];
  }
  float ai0 = 0.f, ai1 = 0.f;
  {
    int m = tid & 127;
    if (m < MM) {
      ai0 = ws[OFF_ATTN + b0 * MM + m];
      ai1 = ws[OFF_ATTN + b1 * MM + m];
    }
  }
  const float bav = b_a[0];
  float xc0 = 0.f, xc1 = 0.f;
  if (tid < 128) {
    int bb = (tid >= 64) ? b1 : b0;
    int lane = tid & 63;
    xc0 = x[((size_t)bb * TT) * MM + lane];
    xc1 = (lane < 17) ? x[((size_t)bb * TT) * MM + 64 + lane] : 0.f;
  }
  const unsigned int* __restrict__ Wah2u = (const unsigned int*)(ws + OFF_W2AH);
  const uint4* __restrict__ We8 = (const uint4*)(ws + OFF_WE8);
  const unsigned int* __restrict__ hc0 = (const unsigned int*)hcb[0];
  const unsigned int* __restrict__ hc1 = (const unsigned int*)hcb[1];
  const unsigned int* __restrict__ u0p = (const unsigned int*)uu[0];
  const unsigned int* __restrict__ u1p = (const unsigned int*)uu[1];
  float creg = 0.f;
  __syncthreads();

  for (int t = 0; t < TT; ++t) {
    {
      float a0 = 0.f, a1 = 0.f;
      const int kb = q * 64;
      #pragma unroll 8
      for (int i = 0; i < 64; ++i) {
        unsigned int w = Wah2u[(kb + i) * 256 + j];
        a0 = fdot2f(w, hc0[kb + i], a0);
        a1 = fdot2f(w, hc1[kb + i], a1);
      }
      aA[(q * 256 + j) * 2 + 0] = a0;
      aA[(q * 256 + j) * 2 + 1] = a1;
      float4 g0 = {0, 0, 0, 0}, g1 = {0, 0, 0, 0};
      const int ku0 = 41 + q * 32;
      #pragma unroll 4
      for (int i = 0; i < 32; ++i) {
        int ku = ku0 + i;
        uint4 wu = We8[ku * 256 + j];
        unsigned int ua = u0p[ku], ub = u1p[ku];
        g0.x = fdot2f(wu.x, ua, g0.x); g0.y = fdot2f(wu.y, ua, g0.y);
        g0.z = fdot2f(wu.z, ua, g0.z); g0.w = fdot2f(wu.w, ua, g0.w);
        g1.x = fdot2f(wu.x, ub, g1.x); g1.y = fdot2f(wu.y, ub, g1.y);
        g1.z = fdot2f(wu.z, ub, g1.z); g1.w = fdot2f(wu.w, ub, g1.w);
      }
      gA[(q * 2 + 0) * 256 + j] = g0;
      gA[(q * 2 + 1) * 256 + j] = g1;
    }
    __syncthreads();
    if (tid < 512) {
      int b = tid >> 8, h = tid & 255;
      hpb[2 * h + b] = aA[(0 * 256 + h) * 2 + b] + aA[(1 * 256 + h) * 2 + b] +
                       aA[(2 * 256 + h) * 2 + b] + aA[(3 * 256 + h) * 2 + b] + bahr;
    }
    __syncthreads();
    {
      int m = tid & 127, tq = tid >> 7;
      if (m < MM) {
        float e0 = 0.f, e1 = 0.f;
        #pragma unroll 8
        for (int i = tq * 16; i < tq * 16 + 16; ++i) {
          float4 hv = *(const float4*)&hpb[i * 4];
          float2 wv = *(const float2*)&wa2[i * 2];
          e0 += ftanh(hv.x + ai0) * wv.x + ftanh(hv.z + ai0) * wv.y;
          e1 += ftanh(hv.y + ai1) * wv.x + ftanh(hv.w + ai1) * wv.y;
        }
        aA[(tq * 2 + 0) * 96 + m] = e0;
        aA[(tq * 2 + 1) * 96 + m] = e1;
      }
    }
    __syncthreads();
    if (tid < 128) {
      int wv_id = tid >> 6, lane = tid & 63;
      float v0 = bav, v1 = bav;
      #pragma unroll
      for (int tq = 0; tq < 8; ++tq) {
        v0 += aA[(tq * 2 + wv_id) * 96 + lane];
        if (lane < 17) v1 += aA[(tq * 2 + wv_id) * 96 + 64 + lane];
      }
      float e0 = __expf(v0);
      float e1 = (lane < 17) ? __expf(v1) : 0.f;
      float sm = e0 + e1;
      #pragma unroll
      for (int d = 1; d < 64; d <<= 1) sm += __shfl_xor(sm, d);
      float inv = frcp(sm);
      uu[wv_id][lane] = f2h(e0 * inv * xc0);
      if (lane < 17) uu[wv_id][64 + lane] = f2h(e1 * inv * xc1);
      if (t < 255) {
        int bb = wv_id ? b1 : b0;
        xc0 = x[((size_t)bb * TT + t + 1) * MM + lane];
        xc1 = (lane < 17) ? x[((size_t)bb * TT + t + 1) * MM + 64 + lane] : 0.f;
      }
    }
    __syncthreads();
    {
      const int kA = (q == 0) ? 0 : (q == 1) ? 11 : (q == 2) ? 21 : 31;
      const int kB = (q == 0) ? 11 : (q == 1) ? 21 : (q == 2) ? 31 : 41;
      float4 g0 = gA[(q * 2 + 0) * 256 + j];
      float4 g1 = gA[(q * 2 + 1) * 256 + j];
      for (int ku = kA; ku < kB; ++ku) {
        uint4 wu = We8[ku * 256 + j];
        unsigned int ua = u0p[ku], ub = u1p[ku];
        g0.x = fdot2f(wu.x, ua, g0.x); g0.y = fdot2f(wu.y, ua, g0.y);
        g0.z = fdot2f(wu.z, ua, g0.z); g0.w = fdot2f(wu.w, ua, g0.w);
        g1.x = fdot2f(wu.x, ub, g1.x); g1.y = fdot2f(wu.y, ub, g1.y);
        g1.z = fdot2f(wu.z, ub, g1.z); g1.w = fdot2f(wu.w, ub, g1.w);
      }
      gA[(q * 2 + 0) * 256 + j] = g0;
      gA[(q * 2 + 1) * 256 + j] = g1;
    }
    __syncthreads();
    if (tid < 512) {
      int b = tid >> 8, jj = tid & 255;
      float4 s0 = gA[(0 * 2 + b) * 256 + jj];
      float4 s1 = gA[(1 * 2 + b) * 256 + jj];
      float4 s2 = gA[(2 * 2 + b) * 256 + jj];
      float4 s3 = gA[(3 * 2 + b) * 256 + jj];
      float gi = s0.x + s1.x + s2.x + s3.x + bias4.x;
      float gf = s0.y + s1.y + s2.y + s3.y + bias4.y;
      float gg = s0.z + s1.z + s2.z + s3.z + bias4.z;
      float go = s0.w + s1.w + s2.w + s3.w + bias4.w;
      float c = fsig(gf) * creg + fsig(gi) * ftanh(gg);
      float h = fsig(go) * ftanh(c);
      creg = c;
      hcb[b][jj] = f2h(h);
      hcb[b][256 + jj] = f2h(c);
      uu[b][81 + jj] = f2h(h);
      ws[OFF_ENC + (((size_t)(b ? b1 : b0) * TT + t) * HEE + jj)] = h;
    }
    __syncthreads();
  }
}

// ---------------- encW[b][t] = enc[b,t,:] . W_fc[:256] ----------------
__global__ __launch_bounds__(256) void k_encw(const float* __restrict__ W_fc, float* __restrict__ ws) {
  const float* __restrict__ enc = ws + OFF_ENC;
  const int wv = threadIdx.x >> 6, lane = threadIdx.x & 63;
  float4 wfc = reinterpret_cast<const float4*>(W_fc)[lane];
  for (int r = blockIdx.x * 4 + wv; r < BB * TT; r += 4096) {
    float4 e = reinterpret_cast<const float4*>(enc + (size_t)r * HEE)[lane];
    float d = e.x * wfc.x + e.y * wfc.y + e.z * wfc.z + e.w * wfc.w;
    #pragma unroll
    for (int dd = 1; dd < 64; dd <<= 1) d += __shfl_xor(d, dd);
    if (lane == 0) ws[OFF_ENCW + r] = d;
  }
}

// ---------------- enc_proj fp16: epH[b][t'][h] ----------------
__global__ __launch_bounds__(256) void k_encproj(const float* __restrict__ W_d1, float* __restrict__ ws) {
  __shared__ __align__(16) float le[16][256];
  const int tid = threadIdx.x;
  const int b = blockIdx.x >> 4;
  const int t0 = (blockIdx.x & 15) * 16;
  const float* __restrict__ enc = ws + OFF_ENC;
  __half* __restrict__ epH = (__half*)(ws + OFF_EPI);
  #pragma unroll
  for (int rr = 0; rr < 16; ++rr)
    le[rr][tid] = enc[((size_t)b * TT + (t0 + rr)) * HEE + tid];
  __syncthreads();
  const float4* wrow = (const float4*)(W_d1 + (size_t)tid * 768 + 512);
  float acc[16];
  #pragma unroll
  for (int r = 0; r < 16; ++r) acc[r] = 0.f;
  for (int e4 = 0; e4 < 64; ++e4) {
    float4 w = wrow[e4];
    #pragma unroll
    for (int r = 0; r < 16; ++r) {
      float4 ev = *(const float4*)&le[r][e4 * 4];
      acc[r] += ev.x * w.x + ev.y * w.y + ev.z * w.z + ev.w * w.w;
    }
  }
  #pragma unroll
  for (int rr = 0; rr < 16; ++rr)
    epH[((size_t)b * TT + (t0 + rr)) * HEE + tid] = __float2half(acc[rr]);
}

// ---------------- decoder: 1024 threads, 2 batches/step, both eps in LDS (fp8) ----------------
__global__ __launch_bounds__(1024) void k_decoder(
    const float* __restrict__ y_history, const float* __restrict__ b_d1,
    const float* __restrict__ W_d2, const float* __restrict__ b_d2,
    const float* __restrict__ W_fc, const float* __restrict__ b_fc,
    const float* __restrict__ Wih_d,
    const float* __restrict__ bih_d, const float* __restrict__ bhh_d,
    const float* __restrict__ W_ff, const float* __restrict__ b_ff,
    float* __restrict__ ws, float* __restrict__ out) {
  __shared__ __align__(16) unsigned char ep8L[131072]; // [256 t'][32 chunks: b0(16)|b1(16)], swizzled (128 KB)
  __shared__ __align__(16) float aA[2048];      // p1/score/ctx partials
  __shared__ __align__(16) uint2 gAh[2048];     // fp16 gate partials
  __shared__ __align__(16) float ddp2[512];     // d packed 2h+b; awls at finale
  __shared__ __align__(16) ushort hcb[2][512];  // fp16 [h;c] per batch
  __shared__ __align__(16) float w2f[256];
  __shared__ __align__(16) float ybuf[512];
  __shared__ float red[2][8];
  const int tid = threadIdx.x;
  const int tp = tid & 255, q = tid >> 8;
  const int lane = tid & 63, wvid = tid >> 6;
  const int b0 = blockIdx.x * 2, b1 = b0 + 1;
  const float wfcy = W_fc[256], bfc = b_fc[0], bd2v = b_d2[0], bffv = b_ff[0];

  if (tid < 256) w2f[tid] = W_d2[tid];
  ((ushort*)hcb)[tid] = 0;
  if (tid < 510) {
    int s = tid >> 1, b = tid & 1;
    ybuf[tid] = y_history[(size_t)(b ? b1 : b0) * 255 + s] * wfcy + bfc;
  }
  const float bd1q = 0.25f * b_d1[tp];
  float4 biasd, wy;
  biasd.x = bih_d[tp] + bhh_d[tp];
  biasd.y = bih_d[256 + tp] + bhh_d[256 + tp];
  biasd.z = bih_d[512 + tp] + bhh_d[512 + tp];
  biasd.w = bih_d[768 + tp] + bhh_d[768 + tp];
  wy.x = Wih_d[tp]; wy.y = Wih_d[256 + tp]; wy.z = Wih_d[512 + tp]; wy.w = Wih_d[768 + tp];
  const float wffh = W_ff[tp], wffc = W_ff[256 + tp];
  const float ewr = ws[OFF_ENCW + (size_t)((q & 1) ? b1 : b0) * 256 + tp];

  const uint4* __restrict__ W8 = (const uint4*)(ws + OFF_W8D1);
  const uint4* __restrict__ Wd8 = (const uint4*)(ws + OFF_WD8);
  const uint4* __restrict__ epg = (const uint4*)(ws + OFF_EPI);   // fp16 master
  const uint4* __restrict__ ep16 = (const uint4*)ep8L;
  const uint4* __restrict__ hc4_0 = (const uint4*)hcb[0];
  const uint4* __restrict__ hc4_1 = (const uint4*)hcb[1];
  const unsigned int* __restrict__ hc0u = (const unsigned int*)hcb[0];
  const unsigned int* __restrict__ hc1u = (const unsigned int*)hcb[1];

  // load both batches' ep: global fp16 -> fp8 -> swizzled LDS
  {
    #pragma unroll
    for (int k = 0; k < 8; ++k) {
      int g = k * 1024 + tid;
      int t = g >> 5, c = g & 31;
      const uint4* src = epg + (size_t)((c < 16) ? b0 : b1) * 8192 + t * 32 + (c & 15) * 2;
      uint4 lo = src[0], hi = src[1];
      uint4 o;
      o.x = pk4_fp8(lo.x, lo.y);
      o.y = pk4_fp8(lo.z, lo.w);
      o.z = pk4_fp8(hi.x, hi.y);
      o.w = pk4_fp8(hi.z, hi.w);
      ((uint4*)ep8L)[(g & ~31) | (c ^ (t & 31))] = o;
    }
  }
  const uint4* __restrict__ ep0g = epg + (size_t)b0 * 8192 + tp * 32 + q * 8;
  const uint4* __restrict__ ep1g = epg + (size_t)b1 * 8192 + tp * 32 + q * 8;
  __syncthreads();

  float hreg = 0.f, creg = 0.f;
  float escls = 0.f, invls = 0.f, esc = 0.f;

  for (int s = 0; s < 255; ++s) {
    // ---- A: p1 partials (shared weights, both batches) + Whh gate partials ----
    {
      float a0 = bd1q, a1 = bd1q;
      const int k8b = q * 16;
      #pragma unroll 4
      for (int i = 0; i < 16; ++i) {
        int k8 = k8b + i;
        uint4 wu = W8[k8 * 256 + tp];
        uint4 h0 = hc4_0[k8], h1 = hc4_1[k8];
        a0 = fdot2f(wu.x, h0.x, a0); a0 = fdot2f(wu.y, h0.y, a0);
        a0 = fdot2f(wu.z, h0.z, a0); a0 = fdot2f(wu.w, h0.w, a0);
        a1 = fdot2f(wu.x, h1.x, a1); a1 = fdot2f(wu.y, h1.y, a1);
        a1 = fdot2f(wu.z, h1.z, a1); a1 = fdot2f(wu.w, h1.w, a1);
      }
      *(float2*)&aA[(q * 256 + tp) * 2] = make_float2(a0, a1);
      float4 g0 = {0, 0, 0, 0}, g1 = {0, 0, 0, 0};
      const int k2b = q * 32;
      #pragma unroll 4
      for (int i = 0; i < 32; ++i) {
        int k2 = k2b + i;
        uint4 wu = Wd8[k2 * 256 + tp];
        unsigned int u0 = hc0u[k2], u1 = hc1u[k2];
        g0.x = fdot2f(wu.x, u0, g0.x); g0.y = fdot2f(wu.y, u0, g0.y);
        g0.z = fdot2f(wu.z, u0, g0.z); g0.w = fdot2f(wu.w, u0, g0.w);
        g1.x = fdot2f(wu.x, u1, g1.x); g1.y = fdot2f(wu.y, u1, g1.y);
        g1.z = fdot2f(wu.z, u1, g1.z); g1.w = fdot2f(wu.w, u1, g1.w);
      }
      uint2 p0, p1;
      p0.x = pkh2(g0.x, g0.y); p0.y = pkh2(g0.z, g0.w);
      p1.x = pkh2(g1.x, g1.y); p1.y = pkh2(g1.z, g1.w);
      gAh[(q * 2 + 0) * 256 + tp] = p0;
      gAh[(q * 2 + 1) * 256 + tp] = p1;
    }
    __syncthreads();
    // ---- B: d combine ----
    if (tid < 512) {
      int b = tid >> 8, h = tid & 255;
      ddp2[2 * h + b] = aA[(0 * 256 + h) * 2 + b] + aA[(1 * 256 + h) * 2 + b] +
                        aA[(2 * 256 + h) * 2 + b] + aA[(3 * 256 + h) * 2 + b];
    }
    __syncthreads();
    // ---- C: score partials; fp8 LDS for s<254, exact fp16 global at s==254 ----
    if (s != 254) {
      float q0 = 0.f, q1 = 0.f;
      const int rowbase = tp * 32, sw = tp & 31;
      #pragma unroll
      for (int k = 0; k < 4; ++k) {
        uint4 e0u = ep16[rowbase + ((q * 4 + k) ^ sw)];
        uint4 e1u = ep16[rowbase + ((16 + q * 4 + k) ^ sw)];
        const int hb = q * 64 + k * 16;
        const unsigned* e0d = (const unsigned*)&e0u;
        const unsigned* e1d = (const unsigned*)&e1u;
        #pragma unroll
        for (int dd = 0; dd < 4; ++dd) {
          const int h4 = hb + dd * 4;
          float2 xa0 = cvt2lo(e0d[dd]), xb0 = cvt2hi(e0d[dd]);
          float2 xa1 = cvt2lo(e1d[dd]), xb1 = cvt2hi(e1d[dd]);
          float4 wf = *(const float4*)&w2f[h4];
          float4 dva = *(const float4*)&ddp2[2 * h4];
          float4 dvb = *(const float4*)&ddp2[2 * h4 + 4];
          q0 += wf.x * ftanh(xa0.x + dva.x) + wf.y * ftanh(xa0.y + dva.z)
              + wf.z * ftanh(xb0.x + dvb.x) + wf.w * ftanh(xb0.y + dvb.z);
          q1 += wf.x * ftanh(xa1.x + dva.y) + wf.y * ftanh(xa1.y + dva.w)
              + wf.z * ftanh(xb1.x + dvb.y) + wf.w * ftanh(xb1.y + dvb.w);
        }
      }
      *(float2*)&aA[(q * 256 + tp) * 2] = make_float2(q0, q1);
    } else {
      float q0 = 0.f, q1 = 0.f;
      #pragma unroll
      for (int k = 0; k < 8; ++k) {
        uint4 e0u = ep0g[k];
        uint4 e1u = ep1g[k];
        const int h8 = q * 64 + k * 8;
        const __half2* e0h = (const __half2*)&e0u;
        const __half2* e1h = (const __half2*)&e1u;
        #pragma unroll
        for (int jj = 0; jj < 4; ++jj) {
          float2 ea = __half22float2(e0h[jj]);
          float2 eb = __half22float2(e1h[jj]);
          float2 wf = *(const float2*)&w2f[h8 + 2 * jj];
          float4 dv = *(const float4*)&ddp2[2 * (h8 + 2 * jj)];
          q0 += wf.x * ftanh(ea.x + dv.x) + wf.y * ftanh(ea.y + dv.z);
          q1 += wf.x * ftanh(eb.x + dv.y) + wf.y * ftanh(eb.y + dv.w);
        }
      }
      *(float2*)&aA[(q * 256 + tp) * 2] = make_float2(q0, q1);
    }
    __syncthreads();
    // ---- D: softmax partial reductions (q<2 -> batch q; no max-shift) ----
    if (q < 2) {
      float v = aA[(0 * 256 + tp) * 2 + q] + aA[(1 * 256 + tp) * 2 + q] +
                aA[(2 * 256 + tp) * 2 + q] + aA[(3 * 256 + tp) * 2 + q] + bd2v;
      esc = __expf(v);
      float den = esc, num = esc * ewr;
      #pragma unroll
      for (int d = 1; d < 64; d <<= 1) { den += __shfl_xor(den, d); num += __shfl_xor(num, d); }
      if (lane == 0) { red[0][wvid] = den; red[1][wvid] = num; }
    }
    __syncthreads();
    // ---- E: y + gate combine + state update (tid<512, b=tid>>8) ----
    if (tid < 512) {
      int b = tid >> 8, j = tid & 255;
      float den = red[0][b * 4 + 0] + red[0][b * 4 + 1] + red[0][b * 4 + 2] + red[0][b * 4 + 3];
      float num = red[1][b * 4 + 0] + red[1][b * 4 + 1] + red[1][b * 4 + 2] + red[1][b * 4 + 3];
      float inv = frcp(den);
      float y = num * inv + ybuf[2 * s + b];
      if (s == 254) { escls = esc; invls = inv; }
      float gi = wy.x * y + biasd.x, gf = wy.y * y + biasd.y;
      float gg = wy.z * y + biasd.z, go = wy.w * y + biasd.w;
      #pragma unroll
      for (int qq = 0; qq < 4; ++qq) {
        uint2 p = gAh[(qq * 2 + b) * 256 + j];
        float2 lo = __half22float2(*(__half2*)&p.x);
        float2 hi = __half22float2(*(__half2*)&p.y);
        gi += lo.x; gf += lo.y; gg += hi.x; go += hi.y;
      }
      float c = fsig(gf) * creg + fsig(gi) * ftanh(gg);
      float h = fsig(go) * ftanh(c);
      creg = c; hreg = h;
      hcb[b][j] = f2h(h);
      hcb[b][256 + j] = f2h(c);
    }
    __syncthreads();
  }

  // ---- finale: last-step aw (into ddp2) + ctx + output ----
  if (tid < 512) ddp2[2 * tp + (tid >> 8)] = escls * invls;
  __syncthreads();
  {
    float c0 = 0.f, c1 = 0.f;
    const float* __restrict__ e0p = ws + OFF_ENC + (size_t)b0 * TT * HEE;
    const float* __restrict__ e1p = ws + OFF_ENC + (size_t)b1 * TT * HEE;
    for (int t = q * 64; t < q * 64 + 64; ++t) {
      float2 aw = *(const float2*)&ddp2[2 * t];
      c0 = fmaf(aw.x, e0p[(size_t)t * HEE + tp], c0);
      c1 = fmaf(aw.y, e1p[(size_t)t * HEE + tp], c1);
    }
    __syncthreads();
    *(float2*)&aA[(q * 256 + tp) * 2] = make_float2(c0, c1);
  }
  __syncthreads();
  if (tid < 512) {
    int b = tid >> 8, h = tid & 255;
    float ctx = aA[(0 * 256 + h) * 2 + b] + aA[(1 * 256 + h) * 2 + b] +
                aA[(2 * 256 + h) * 2 + b] + aA[(3 * 256 + h) * 2 + b];
    float p = hreg * wffh + ctx * wffc;
    #pragma unroll
    for (int d = 1; d < 64; d <<= 1) p += __shfl_xor(p, d);
    if (lane == 0) red[0][wvid] = p;
  }
  __syncthreads();
  if (tid == 0)   out[b0] = red[0][0] + red[0][1] + red[0][2] + red[0][3] + bffv;
  if (tid == 256) out[b1] = red[0][4] + red[0][5] + red[0][6] + red[0][7] + bffv;
}

extern "C" void kernel_launch(void* const* d_in, const int* in_sizes, int n_in,
                              void* d_out, int out_size, void* d_ws, size_t ws_size,
                              hipStream_t stream) {
  if (ws_size < (size_t)WS_FLOATS * sizeof(float)) return;
  const float* x     = (const float*)d_in[0];
  const float* y_h   = (const float*)d_in[1];
  const float* W_ah  = (const float*)d_in[2];
  const float* b_ah  = (const float*)d_in[3];
  const float* W_ai  = (const float*)d_in[4];
  const float* b_ai  = (const float*)d_in[5];
  const float* W_a   = (const float*)d_in[6];
  const float* b_a   = (const float*)d_in[7];
  const float* Wih_e = (const float*)d_in[8];
  const float* Whh_e = (const float*)d_in[9];
  const float* bih_e = (const float*)d_in[10];
  const float* bhh_e = (const float*)d_in[11];
  const float* W_d1  = (const float*)d_in[12];
  const float* b_d1  = (const float*)d_in[13];
  const float* W_d2  = (const float*)d_in[14];
  const float* b_d2  = (const float*)d_in[15];
  const float* W_fc  = (const float*)d_in[16];
  const float* b_fc  = (const float*)d_in[17];
  const float* Wih_d = (const float*)d_in[18];
  const float* Whh_d = (const float*)d_in[19];
  const float* bih_d = (const float*)d_in[20];
  const float* bhh_d = (const float*)d_in[21];
  const float* W_ff  = (const float*)d_in[22];
  const float* b_ff  = (const float*)d_in[23];
  float* ws  = (float*)d_ws;
  float* out = (float*)d_out;

  k_prep<<<256, 512, 0, stream>>>(W_ah, Wih_e, Whh_e, W_d1, Wih_d, Whh_d, ws);
  k_attn<<<512, 128, 0, stream>>>(x, W_ai, b_ai, ws);
  k_encoder<<<256, 1024, 0, stream>>>(x, b_ah, W_a, b_a, bih_e, bhh_e, ws);
  k_encw<<<1024, 256, 0, stream>>>(W_fc, ws);
  k_encproj<<<8192, 256, 0, stream>>>(W_d1, ws);
  k_decoder<<<256, 1024, 0, stream>>>(y_h, b_d1, W_d2, b_d2, W_fc, b_fc,
                                      Wih_d, bih_d, bhh_d, W_ff, b_ff, ws, out);
}

// Round 13
// 9470.842 us; speedup vs baseline: 1.8369x; 1.1703x over previous
//
#include <hip/hip_runtime.h>
#include <hip/hip_bf16.h>
#include <hip/hip_fp16.h>

#define BB  512
#define TT  256
#define MM  81
#define HEE 256

// ---- workspace layout (float offsets) ----
#define OFF_W8AH   0          // uint4[64 k8][256 j]   encoder p1, 8 halves k=8k8..8k8+7 (k over [h;c])
#define OFF_WE8    65536      // uint4[169 k2][256 j]  encoder LSTM, gate-major pairs
#define OFF_W8D1   238592     // uint4[64 k8][256 j]   decoder p1, 8 halves
#define OFF_WD8G   304128     // uint4[4 gate][32 k8][256 j] decoder Whh per-gate, 8 halves
#define OFF_ATTN   436224     // [512][81] attn_in
#define OFF_ENCW   477696     // [512][256] enc . W_fc[:256]
#define OFF_ENC    608768     // [512][256][256] input_encoded fp32
#define OFF_EPI    34163200   // half[512 b][256 t'][256 h] enc_proj (fp16 master)
#define WS_FLOATS  50940416

typedef _Float16 hh2 __attribute__((ext_vector_type(2)));

__device__ __forceinline__ float frcp(float x) { return __builtin_amdgcn_rcpf(x); }
__device__ __forceinline__ float fsig(float x) { return frcp(1.f + __expf(-x)); }
__device__ __forceinline__ float ftanh(float x) { return 1.f - 2.f * frcp(__expf(2.f * x) + 1.f); }
__device__ __forceinline__ hh2 uash2(unsigned int u) { union { unsigned int u; hh2 h; } x; x.u = u; return x.h; }
__device__ __forceinline__ float fdot2f(unsigned int a, unsigned int b, float c) {
#if __has_builtin(__builtin_amdgcn_fdot2)
  return __builtin_amdgcn_fdot2(uash2(a), uash2(b), c, false);
#else
  hh2 ha = uash2(a), hb = uash2(b);
  return c + (float)ha.x * (float)hb.x + (float)ha.y * (float)hb.y;
#endif
}
__device__ __forceinline__ ushort f2h(float x) { return __half_as_ushort(__float2half(x)); }

// ---- fp8 e4m3 helpers (HW builtins; self-consistent SW fallback) ----
#if __has_builtin(__builtin_amdgcn_cvt_pk_f32_fp8) && __has_builtin(__builtin_amdgcn_cvt_pk_fp8_f32)
typedef float ff2 __attribute__((ext_vector_type(2)));
__device__ __forceinline__ float2 cvt2lo(unsigned v) { ff2 r = __builtin_amdgcn_cvt_pk_f32_fp8(v, false); return make_float2(r[0], r[1]); }
__device__ __forceinline__ float2 cvt2hi(unsigned v) { ff2 r = __builtin_amdgcn_cvt_pk_f32_fp8(v, true);  return make_float2(r[0], r[1]); }
__device__ __forceinline__ unsigned pk4_fp8(unsigned a, unsigned b) {
  float2 fa = __half22float2(*(__half2*)&a);
  float2 fb = __half22float2(*(__half2*)&b);
  int r = __builtin_amdgcn_cvt_pk_fp8_f32(fa.x, fa.y, 0, false);
  r = __builtin_amdgcn_cvt_pk_fp8_f32(fb.x, fb.y, r, true);
  return (unsigned)r;
}
#else
__device__ __forceinline__ float dec1_fp8(unsigned b) {
  unsigned s = b >> 7, ef = (b >> 3) & 0xf, m = b & 7;
  float v = (ef == 0) ? (float)m * 0.001953125f
                      : (1.f + (float)m * 0.125f) * exp2f((float)((int)ef - 7));
  return s ? -v : v;
}
__device__ __forceinline__ float2 cvt2lo(unsigned v) { return make_float2(dec1_fp8(v & 0xff), dec1_fp8((v >> 8) & 0xff)); }
__device__ __forceinline__ float2 cvt2hi(unsigned v) { return make_float2(dec1_fp8((v >> 16) & 0xff), dec1_fp8((v >> 24) & 0xff)); }
__device__ __forceinline__ unsigned enc1_fp8(float x) {
  unsigned u = __float_as_uint(x); unsigned sgn = (u >> 31) << 7;
  float ax = fabsf(x);
  if (ax < 0.0009765625f) return sgn;
  if (ax >= 448.f) return sgn | 0x7e;
  if (ax < 0.015625f) { int k = (int)rintf(ax * 512.f); return (k >= 8) ? (sgn | 0x08) : (sgn | (unsigned)k); }
  int e = (int)((u >> 23) & 0xff) - 127;
  unsigned m = u & 0x7fffff;
  unsigned mr = m + 0x7ffff + ((m >> 20) & 1);
  if (mr >= 0x800000) { mr = 0; ++e; if (e > 8) return sgn | 0x7e; }
  return sgn | (unsigned)((e + 7) << 3) | (mr >> 20);
}
__device__ __forceinline__ unsigned pk4_fp8(unsigned a, unsigned b) {
  float2 fa = __half22float2(*(__half2*)&a);
  float2 fb = __half22float2(*(__half2*)&b);
  return enc1_fp8(fa.x) | (enc1_fp8(fa.y) << 8) | (enc1_fp8(fb.x) << 16) | (enc1_fp8(fb.y) << 24);
}
#endif

// ---------------- weight prep ----------------
__global__ void k_prep(const float* __restrict__ W_ah, const float* __restrict__ Wih_e,
                       const float* __restrict__ Whh_e, const float* __restrict__ W_d1,
                       const float* __restrict__ Wih_d, const float* __restrict__ Whh_d,
                       float* __restrict__ ws) {
  int idx = blockIdx.x * 512 + threadIdx.x;
  if (idx < 16384) {  // encoder p1: uint4[64 k8][256 j]
    int k8 = idx >> 8, j = idx & 255;
    const float* wr = W_ah + (size_t)j * 512 + 8 * k8;
    union { __half2 h[4]; uint4 u; } w;
    w.h[0] = __floats2half2_rn(wr[0], wr[1]);
    w.h[1] = __floats2half2_rn(wr[2], wr[3]);
    w.h[2] = __floats2half2_rn(wr[4], wr[5]);
    w.h[3] = __floats2half2_rn(wr[6], wr[7]);
    ((uint4*)(ws + OFF_W8AH))[idx] = w.u;
  }
  if (idx < 16384) {  // decoder p1: uint4[64 k8][256 j]
    int k8 = idx >> 8, j = idx & 255;
    const float* wr = W_d1 + (size_t)j * 768 + 8 * k8;
    union { __half2 h[4]; uint4 u; } w;
    w.h[0] = __floats2half2_rn(wr[0], wr[1]);
    w.h[1] = __floats2half2_rn(wr[2], wr[3]);
    w.h[2] = __floats2half2_rn(wr[4], wr[5]);
    w.h[3] = __floats2half2_rn(wr[6], wr[7]);
    ((uint4*)(ws + OFF_W8D1))[idx] = w.u;
  }
  if (idx < 43264) {  // encoder LSTM: gate-major pairs over u=[wi(81);h(256);pad]
    int k2 = idx >> 8, j = idx & 255;
    auto we = [&](int g, int kk) -> float {
      if (kk < 81)  return Wih_e[(g * 256 + j) * 81 + kk];
      if (kk < 337) return Whh_e[(g * 256 + j) * 256 + (kk - 81)];
      return 0.f;
    };
    int ke = 2 * k2, ko = 2 * k2 + 1;
    union { __half2 h[4]; uint4 u; } w;
    w.h[0] = __floats2half2_rn(we(0, ke), we(0, ko));
    w.h[1] = __floats2half2_rn(we(1, ke), we(1, ko));
    w.h[2] = __floats2half2_rn(we(2, ke), we(2, ko));
    w.h[3] = __floats2half2_rn(we(3, ke), we(3, ko));
    ((uint4*)(ws + OFF_WE8))[idx] = w.u;
  }
  if (idx < 32768) {  // decoder Whh per-gate: uint4[gate][32 k8][256 j]
    int r = idx >> 8, j = idx & 255;
    int gate = r >> 5, k8 = r & 31;
    const float* wr = Whh_d + (size_t)(gate * 256 + j) * 256 + 8 * k8;
    union { __half2 h[4]; uint4 u; } w;
    w.h[0] = __floats2half2_rn(wr[0], wr[1]);
    w.h[1] = __floats2half2_rn(wr[2], wr[3]);
    w.h[2] = __floats2half2_rn(wr[4], wr[5]);
    w.h[3] = __floats2half2_rn(wr[6], wr[7]);
    ((uint4*)(ws + OFF_WD8G))[idx] = w.u;
  }
}

// ---------------- attn_in[b][m] ----------------
__global__ void k_attn(const float* __restrict__ x, const float* __restrict__ W_ai,
                       const float* __restrict__ b_ai, float* __restrict__ ws) {
  __shared__ float wai[256];
  const int b = blockIdx.x, tid = threadIdx.x;  // 128 threads
  wai[tid] = W_ai[tid];
  wai[128 + tid] = W_ai[128 + tid];
  __syncthreads();
  if (tid < MM) {
    float acc = b_ai[0];
    const float* xp = x + (size_t)b * TT * MM + tid;
    #pragma unroll 8
    for (int t = 0; t < TT; ++t) acc = fmaf(xp[t * MM], wai[t], acc);
    ws[OFF_ATTN + b * MM + tid] = acc;
  }
}

// ---------------- encoder: 1024 threads, 2 batch rows, 256 steps ----------------
__global__ __launch_bounds__(1024, 2) void k_encoder(
    const float* __restrict__ x, const float* __restrict__ b_ah,
    const float* __restrict__ W_a, const float* __restrict__ b_a,
    const float* __restrict__ bih_e, const float* __restrict__ bhh_e,
    float* __restrict__ ws) {
  __shared__ __align__(16) float aA[2048];
  __shared__ __align__(16) float4 gA[2048];
  __shared__ __align__(16) float hpb[512];
  __shared__ __align__(16) float wa2[256];
  __shared__ __align__(16) ushort hcb[2][512];
  __shared__ __align__(16) ushort uu[2][344];
  const int tid = threadIdx.x;
  const int j = tid & 255, q = tid >> 8;
  const int b0 = blockIdx.x * 2, b1 = b0 + 1;

  if (tid < 256) wa2[tid] = W_a[tid];
  if (tid < 512) { hcb[0][tid] = 0; hcb[1][tid] = 0; }
  if (tid < 344) { uu[0][tid] = 0; uu[1][tid] = 0; }
  float bahr = 0.f; float4 bias4 = {0, 0, 0, 0};
  if (tid < 512) {
    bahr = b_ah[j];
    bias4.x = bih_e[j] + bhh_e[j];
    bias4.y = bih_e[256 + j] + bhh_e[256 + j];
    bias4.z = bih_e[512 + j] + bhh_e[512 + j];
    bias4.w = bih_e[768 + j] + bhh_e[768 + j];
  }
  float ai0 = 0.f, ai1 = 0.f;
  {
    int m = tid & 127;
    if (m < MM) {
      ai0 = ws[OFF_ATTN + b0 * MM + m];
      ai1 = ws[OFF_ATTN + b1 * MM + m];
    }
  }
  const float bav = b_a[0];
  float xc0 = 0.f, xc1 = 0.f;
  if (tid < 128) {
    int bb = (tid >= 64) ? b1 : b0;
    int lane = tid & 63;
    xc0 = x[((size_t)bb * TT) * MM + lane];
    xc1 = (lane < 17) ? x[((size_t)bb * TT) * MM + 64 + lane] : 0.f;
  }
  const uint4* __restrict__ W8A = (const uint4*)(ws + OFF_W8AH);
  const uint4* __restrict__ We8 = (const uint4*)(ws + OFF_WE8);
  const uint4* __restrict__ hcq0 = (const uint4*)hcb[0];
  const uint4* __restrict__ hcq1 = (const uint4*)hcb[1];
  const unsigned int* __restrict__ u0p = (const unsigned int*)uu[0];
  const unsigned int* __restrict__ u1p = (const unsigned int*)uu[1];
  float creg = 0.f;
  __syncthreads();

  for (int t = 0; t < TT; ++t) {
    // ---- A: p1 partials (uint4-packed weights) + LSTM h-part partials ----
    {
      float a0 = 0.f, a1 = 0.f;
      const int k8b = q * 16;
      #pragma unroll 4
      for (int i = 0; i < 16; ++i) {
        int k8 = k8b + i;
        uint4 wu = W8A[k8 * 256 + j];
        uint4 h0 = hcq0[k8], h1 = hcq1[k8];
        a0 = fdot2f(wu.x, h0.x, a0); a0 = fdot2f(wu.y, h0.y, a0);
        a0 = fdot2f(wu.z, h0.z, a0); a0 = fdot2f(wu.w, h0.w, a0);
        a1 = fdot2f(wu.x, h1.x, a1); a1 = fdot2f(wu.y, h1.y, a1);
        a1 = fdot2f(wu.z, h1.z, a1); a1 = fdot2f(wu.w, h1.w, a1);
      }
      aA[(q * 256 + j) * 2 + 0] = a0;
      aA[(q * 256 + j) * 2 + 1] = a1;
      float4 g0 = {0, 0, 0, 0}, g1 = {0, 0, 0, 0};
      const int ku0 = 41 + q * 32;
      #pragma unroll 4
      for (int i = 0; i < 32; ++i) {
        int ku = ku0 + i;
        uint4 wu = We8[ku * 256 + j];
        unsigned int ua = u0p[ku], ub = u1p[ku];
        g0.x = fdot2f(wu.x, ua, g0.x); g0.y = fdot2f(wu.y, ua, g0.y);
        g0.z = fdot2f(wu.z, ua, g0.z); g0.w = fdot2f(wu.w, ua, g0.w);
        g1.x = fdot2f(wu.x, ub, g1.x); g1.y = fdot2f(wu.y, ub, g1.y);
        g1.z = fdot2f(wu.z, ub, g1.z); g1.w = fdot2f(wu.w, ub, g1.w);
      }
      gA[(q * 2 + 0) * 256 + j] = g0;
      gA[(q * 2 + 1) * 256 + j] = g1;
    }
    __syncthreads();
    if (tid < 512) {
      int b = tid >> 8, h = tid & 255;
      hpb[2 * h + b] = aA[(0 * 256 + h) * 2 + b] + aA[(1 * 256 + h) * 2 + b] +
                       aA[(2 * 256 + h) * 2 + b] + aA[(3 * 256 + h) * 2 + b] + bahr;
    }
    __syncthreads();
    {
      int m = tid & 127, tq = tid >> 7;
      if (m < MM) {
        float e0 = 0.f, e1 = 0.f;
        #pragma unroll 8
        for (int i = tq * 16; i < tq * 16 + 16; ++i) {
          float4 hv = *(const float4*)&hpb[i * 4];
          float2 wv = *(const float2*)&wa2[i * 2];
          e0 += ftanh(hv.x + ai0) * wv.x + ftanh(hv.z + ai0) * wv.y;
          e1 += ftanh(hv.y + ai1) * wv.x + ftanh(hv.w + ai1) * wv.y;
        }
        aA[(tq * 2 + 0) * 96 + m] = e0;
        aA[(tq * 2 + 1) * 96 + m] = e1;
      }
    }
    __syncthreads();
    if (tid < 128) {
      int wv_id = tid >> 6, lane = tid & 63;
      float v0 = bav, v1 = bav;
      #pragma unroll
      for (int tq = 0; tq < 8; ++tq) {
        v0 += aA[(tq * 2 + wv_id) * 96 + lane];
        if (lane < 17) v1 += aA[(tq * 2 + wv_id) * 96 + 64 + lane];
      }
      float e0 = __expf(v0);
      float e1 = (lane < 17) ? __expf(v1) : 0.f;
      float sm = e0 + e1;
      #pragma unroll
      for (int d = 1; d < 64; d <<= 1) sm += __shfl_xor(sm, d);
      float inv = frcp(sm);
      uu[wv_id][lane] = f2h(e0 * inv * xc0);
      if (lane < 17) uu[wv_id][64 + lane] = f2h(e1 * inv * xc1);
      if (t < 255) {
        int bb = wv_id ? b1 : b0;
        xc0 = x[((size_t)bb * TT + t + 1) * MM + lane];
        xc1 = (lane < 17) ? x[((size_t)bb * TT + t + 1) * MM + 64 + lane] : 0.f;
      }
    }
    __syncthreads();
    {
      const int kA = (q == 0) ? 0 : (q == 1) ? 11 : (q == 2) ? 21 : 31;
      const int kB = (q == 0) ? 11 : (q == 1) ? 21 : (q == 2) ? 31 : 41;
      float4 g0 = gA[(q * 2 + 0) * 256 + j];
      float4 g1 = gA[(q * 2 + 1) * 256 + j];
      for (int ku = kA; ku < kB; ++ku) {
        uint4 wu = We8[ku * 256 + j];
        unsigned int ua = u0p[ku], ub = u1p[ku];
        g0.x = fdot2f(wu.x, ua, g0.x); g0.y = fdot2f(wu.y, ua, g0.y);
        g0.z = fdot2f(wu.z, ua, g0.z); g0.w = fdot2f(wu.w, ua, g0.w);
        g1.x = fdot2f(wu.x, ub, g1.x); g1.y = fdot2f(wu.y, ub, g1.y);
        g1.z = fdot2f(wu.z, ub, g1.z); g1.w = fdot2f(wu.w, ub, g1.w);
      }
      gA[(q * 2 + 0) * 256 + j] = g0;
      gA[(q * 2 + 1) * 256 + j] = g1;
    }
    __syncthreads();
    if (tid < 512) {
      int b = tid >> 8, jj = tid & 255;
      float4 s0 = gA[(0 * 2 + b) * 256 + jj];
      float4 s1 = gA[(1 * 2 + b) * 256 + jj];
      float4 s2 = gA[(2 * 2 + b) * 256 + jj];
      float4 s3 = gA[(3 * 2 + b) * 256 + jj];
      float gi = s0.x + s1.x + s2.x + s3.x + bias4.x;
      float gf = s0.y + s1.y + s2.y + s3.y + bias4.y;
      float gg = s0.z + s1.z + s2.z + s3.z + bias4.z;
      float go = s0.w + s1.w + s2.w + s3.w + bias4.w;
      float c = fsig(gf) * creg + fsig(gi) * ftanh(gg);
      float h = fsig(go) * ftanh(c);
      creg = c;
      hcb[b][jj] = f2h(h);
      hcb[b][256 + jj] = f2h(c);
      uu[b][81 + jj] = f2h(h);
      ws[OFF_ENC + (((size_t)(b ? b1 : b0) * TT + t) * HEE + jj)] = h;
    }
    __syncthreads();
  }
}

// ---------------- encW[b][t] = enc[b,t,:] . W_fc[:256] ----------------
__global__ __launch_bounds__(256) void k_encw(const float* __restrict__ W_fc, float* __restrict__ ws) {
  const float* __restrict__ enc = ws + OFF_ENC;
  const int wv = threadIdx.x >> 6, lane = threadIdx.x & 63;
  float4 wfc = reinterpret_cast<const float4*>(W_fc)[lane];
  for (int r = blockIdx.x * 4 + wv; r < BB * TT; r += 4096) {
    float4 e = reinterpret_cast<const float4*>(enc + (size_t)r * HEE)[lane];
    float d = e.x * wfc.x + e.y * wfc.y + e.z * wfc.z + e.w * wfc.w;
    #pragma unroll
    for (int dd = 1; dd < 64; dd <<= 1) d += __shfl_xor(d, dd);
    if (lane == 0) ws[OFF_ENCW + r] = d;
  }
}

// ---------------- enc_proj fp16: epH[b][t'][h] ----------------
__global__ __launch_bounds__(256) void k_encproj(const float* __restrict__ W_d1, float* __restrict__ ws) {
  __shared__ __align__(16) float le[16][256];
  const int tid = threadIdx.x;
  const int b = blockIdx.x >> 4;
  const int t0 = (blockIdx.x & 15) * 16;
  const float* __restrict__ enc = ws + OFF_ENC;
  __half* __restrict__ epH = (__half*)(ws + OFF_EPI);
  #pragma unroll
  for (int rr = 0; rr < 16; ++rr)
    le[rr][tid] = enc[((size_t)b * TT + (t0 + rr)) * HEE + tid];
  __syncthreads();
  const float4* wrow = (const float4*)(W_d1 + (size_t)tid * 768 + 512);
  float acc[16];
  #pragma unroll
  for (int r = 0; r < 16; ++r) acc[r] = 0.f;
  for (int e4 = 0; e4 < 64; ++e4) {
    float4 w = wrow[e4];
    #pragma unroll
    for (int r = 0; r < 16; ++r) {
      float4 ev = *(const float4*)&le[r][e4 * 4];
      acc[r] += ev.x * w.x + ev.y * w.y + ev.z * w.z + ev.w * w.w;
    }
  }
  #pragma unroll
  for (int rr = 0; rr < 16; ++rr)
    epH[((size_t)b * TT + (t0 + rr)) * HEE + tid] = __float2half(acc[rr]);
}

// ---------------- decoder: 512 WGs x 1024 threads, 1 batch/WG, 2 WGs/CU ----------------
__global__ __launch_bounds__(1024, 8) void k_decoder(
    const float* __restrict__ y_history, const float* __restrict__ b_d1,
    const float* __restrict__ W_d2, const float* __restrict__ b_d2,
    const float* __restrict__ W_fc, const float* __restrict__ b_fc,
    const float* __restrict__ Wih_d,
    const float* __restrict__ bih_d, const float* __restrict__ bhh_d,
    const float* __restrict__ W_ff, const float* __restrict__ b_ff,
    float* __restrict__ ws, float* __restrict__ out) {
  __shared__ __align__(16) unsigned char ep8L[65536]; // [256 t'][16 chunks], swizzled (64 KB)
  __shared__ __align__(16) float aA[1024];      // p1/score/ctx partials (4 KB)
  __shared__ __align__(16) float gL[1024];      // gate full sums [gate*256+j] (4 KB)
  __shared__ __align__(16) float ddp[256];      // d vector; awls at finale (1 KB)
  __shared__ __align__(16) ushort hc[512];      // fp16 [h(256); c(256)] (1 KB)
  __shared__ __align__(16) float w2f[256];      // (1 KB)
  __shared__ __align__(16) float ybuf[256];     // (1 KB)
  __shared__ float red[2][4];
  const int tid = threadIdx.x;
  const int tp = tid & 255, q = tid >> 8;       // q in 0..3
  const int lane = tid & 63, wvid = tid >> 6;
  const int b = blockIdx.x;
  const float wfcy = W_fc[256], bfc = b_fc[0], bd2v = b_d2[0], bffv = b_ff[0];

  if (tid < 256) w2f[tid] = W_d2[tid];
  if (tid < 512) hc[tid] = 0;
  if (tid < 255) ybuf[tid] = y_history[(size_t)b * 255 + tid] * wfcy + bfc;
  const float bd1r = b_d1[tp];
  float4 biasd, wy;
  biasd.x = bih_d[tp] + bhh_d[tp];
  biasd.y = bih_d[256 + tp] + bhh_d[256 + tp];
  biasd.z = bih_d[512 + tp] + bhh_d[512 + tp];
  biasd.w = bih_d[768 + tp] + bhh_d[768 + tp];
  wy.x = Wih_d[tp]; wy.y = Wih_d[256 + tp]; wy.z = Wih_d[512 + tp]; wy.w = Wih_d[768 + tp];
  const float wffh = W_ff[tp], wffc = W_ff[256 + tp];
  const float ewr = ws[OFF_ENCW + (size_t)b * 256 + tp];

  const uint4* __restrict__ W8 = (const uint4*)(ws + OFF_W8D1);
  const uint4* __restrict__ WG = (const uint4*)(ws + OFF_WD8G);
  const uint4* __restrict__ epg = (const uint4*)(ws + OFF_EPI);  // fp16 master
  const uint4* __restrict__ ep16 = (const uint4*)ep8L;
  const uint4* __restrict__ hc4 = (const uint4*)hc;              // 0..63 over [h;c]

  // own-batch ep: global fp16 -> fp8 -> swizzled LDS (4096 uint4)
  {
    #pragma unroll
    for (int k = 0; k < 4; ++k) {
      int g = k * 1024 + tid;
      int t = g >> 4, c = g & 15;
      const uint4* src = epg + (size_t)b * 8192 + t * 32 + c * 2;
      uint4 lo = src[0], hi = src[1];
      uint4 o;
      o.x = pk4_fp8(lo.x, lo.y);
      o.y = pk4_fp8(lo.z, lo.w);
      o.z = pk4_fp8(hi.x, hi.y);
      o.w = pk4_fp8(hi.z, hi.w);
      ((uint4*)ep8L)[(g & ~15) | (c ^ (t & 15))] = o;
    }
  }
  const uint4* __restrict__ epXg = epg + (size_t)b * 8192 + tp * 32 + q * 8;  // exact path
  __syncthreads();

  float hreg = 0.f, creg = 0.f;
  float escls = 0.f, invls = 0.f, esc = 0.f;

  for (int s = 0; s < 255; ++s) {
    // ---- A: p1 partial (4-way k split) + one full gate per thread ----
    {
      float a0 = 0.f;
      const int k8b = q * 16;
      #pragma unroll 4
      for (int i = 0; i < 16; ++i) {
        int k8 = k8b + i;
        uint4 wu = W8[k8 * 256 + tp];
        uint4 hv = hc4[k8];
        a0 = fdot2f(wu.x, hv.x, a0); a0 = fdot2f(wu.y, hv.y, a0);
        a0 = fdot2f(wu.z, hv.z, a0); a0 = fdot2f(wu.w, hv.w, a0);
      }
      aA[q * 256 + tp] = a0;
      float g = 0.f;
      const uint4* wg = WG + (q * 32) * 256 + tp;   // gate q, output j=tp
      #pragma unroll 4
      for (int i = 0; i < 32; ++i) {
        uint4 wu = wg[i * 256];
        uint4 hv = hc4[i];                           // h region only (uint4 0..31)
        g = fdot2f(wu.x, hv.x, g); g = fdot2f(wu.y, hv.y, g);
        g = fdot2f(wu.z, hv.z, g); g = fdot2f(wu.w, hv.w, g);
      }
      gL[q * 256 + tp] = g;
    }
    __syncthreads();
    // ---- B: d combine ----
    if (tid < 256)
      ddp[tid] = aA[tid] + aA[256 + tid] + aA[512 + tid] + aA[768 + tid] + bd1r;
    __syncthreads();
    // ---- C: score partials; fp8 LDS for s<254, exact fp16 global at s==254 ----
    if (s != 254) {
      float q0 = 0.f;
      const int base = tp * 16, sw = tp & 15;
      #pragma unroll
      for (int k = 0; k < 4; ++k) {
        uint4 eu = ep16[base + ((q * 4 + k) ^ sw)];
        const int hb = q * 64 + k * 16;
        const unsigned* ed = (const unsigned*)&eu;
        #pragma unroll
        for (int dd = 0; dd < 4; ++dd) {
          const int h4 = hb + dd * 4;
          float2 xa = cvt2lo(ed[dd]), xb = cvt2hi(ed[dd]);
          float4 wf = *(const float4*)&w2f[h4];
          float4 dv = *(const float4*)&ddp[h4];
          q0 += wf.x * ftanh(xa.x + dv.x) + wf.y * ftanh(xa.y + dv.y)
              + wf.z * ftanh(xb.x + dv.z) + wf.w * ftanh(xb.y + dv.w);
        }
      }
      aA[q * 256 + tp] = q0;
    } else {
      float q0 = 0.f;
      #pragma unroll
      for (int k = 0; k < 8; ++k) {
        uint4 eu = epXg[k];
        const int h8 = q * 64 + k * 8;
        const __half2* eh = (const __half2*)&eu;
        #pragma unroll
        for (int jj = 0; jj < 4; ++jj) {
          float2 ea = __half22float2(eh[jj]);
          float2 wf = *(const float2*)&w2f[h8 + 2 * jj];
          float2 dv = *(const float2*)&ddp[h8 + 2 * jj];
          q0 += wf.x * ftanh(ea.x + dv.x) + wf.y * ftanh(ea.y + dv.y);
        }
      }
      aA[q * 256 + tp] = q0;
    }
    __syncthreads();
    // ---- D: softmax partial reductions (tid<256; no max-shift) ----
    if (tid < 256) {
      float v = aA[tp] + aA[256 + tp] + aA[512 + tp] + aA[768 + tp] + bd2v;
      esc = __expf(v);
      float den = esc, num = esc * ewr;
      #pragma unroll
      for (int d = 1; d < 64; d <<= 1) { den += __shfl_xor(den, d); num += __shfl_xor(num, d); }
      if (lane == 0) { red[0][wvid] = den; red[1][wvid] = num; }
    }
    __syncthreads();
    // ---- E: y + gate combine + state update ----
    if (tid < 256) {
      float den = red[0][0] + red[0][1] + red[0][2] + red[0][3];
      float num = red[1][0] + red[1][1] + red[1][2] + red[1][3];
      float inv = frcp(den);
      float y = num * inv + ybuf[s];
      if (s == 254) { escls = esc; invls = inv; }
      float gi = gL[tp]       + wy.x * y + biasd.x;
      float gf = gL[256 + tp] + wy.y * y + biasd.y;
      float gg = gL[512 + tp] + wy.z * y + biasd.z;
      float go = gL[768 + tp] + wy.w * y + biasd.w;
      float c = fsig(gf) * creg + fsig(gi) * ftanh(gg);
      float h = fsig(go) * ftanh(c);
      creg = c; hreg = h;
      hc[tp] = f2h(h);
      hc[256 + tp] = f2h(c);
    }
    __syncthreads();
  }

  // ---- finale: last-step aw (reuse ddp) + ctx + output ----
  if (tid < 256) ddp[tp] = escls * invls;
  __syncthreads();
  {
    float c0 = 0.f;
    const float* __restrict__ e32 = ws + OFF_ENC + (size_t)b * TT * HEE;
    for (int t = q * 64; t < q * 64 + 64; ++t)
      c0 = fmaf(ddp[t], e32[(size_t)t * HEE + tp], c0);
    __syncthreads();
    aA[q * 256 + tp] = c0;
  }
  __syncthreads();
  if (tid < 256) {
    float ctx = aA[tp] + aA[256 + tp] + aA[512 + tp] + aA[768 + tp];
    float p = hreg * wffh + ctx * wffc;
    #pragma unroll
    for (int d = 1; d < 64; d <<= 1) p += __shfl_xor(p, d);
    if (lane == 0) red[0][wvid] = p;
  }
  __syncthreads();
  if (tid == 0) out[b] = red[0][0] + red[0][1] + red[0][2] + red[0][3] + bffv;
}

extern "C" void kernel_launch(void* const* d_in, const int* in_sizes, int n_in,
                              void* d_out, int out_size, void* d_ws, size_t ws_size,
                              hipStream_t stream) {
  if (ws_size < (size_t)WS_FLOATS * sizeof(float)) return;
  const float* x     = (const float*)d_in[0];
  const float* y_h   = (const float*)d_in[1];
  const float* W_ah  = (const float*)d_in[2];
  const float* b_ah  = (const float*)d_in[3];
  const float* W_ai  = (const float*)d_in[4];
  const float* b_ai  = (const float*)d_in[5];
  const float* W_a   = (const float*)d_in[6];
  const float* b_a   = (const float*)d_in[7];
  const float* Wih_e = (const float*)d_in[8];
  const float* Whh_e = (const float*)d_in[9];
  const float* bih_e = (const float*)d_in[10];
  const float* bhh_e = (const float*)d_in[11];
  const float* W_d1  = (const float*)d_in[12];
  const float* b_d1  = (const float*)d_in[13];
  const float* W_d2  = (const float*)d_in[14];
  const float* b_d2  = (const float*)d_in[15];
  const float* W_fc  = (const float*)d_in[16];
  const float* b_fc  = (const float*)d_in[17];
  const float* Wih_d = (const float*)d_in[18];
  const float* Whh_d = (const float*)d_in[19];
  const float* bih_d = (const float*)d_in[20];
  const float* bhh_d = (const float*)d_in[21];
  const float* W_ff  = (const float*)d_in[22];
  const float* b_ff  = (const float*)d_in[23];
  float* ws  = (float*)d_ws;
  float* out = (float*)d_out;

  k_prep<<<256, 512, 0, stream>>>(W_ah, Wih_e, Whh_e, W_d1, Wih_d, Whh_d, ws);
  k_attn<<<512, 128, 0, stream>>>(x, W_ai, b_ai, ws);
  k_encoder<<<256, 1024, 0, stream>>>(x, b_ah, W_a, b_a, bih_e, bhh_e, ws);
  k_encw<<<1024, 256, 0, stream>>>(W_fc, ws);
  k_encproj<<<8192, 256, 0, stream>>>(W_d1, ws);
  k_decoder<<<512, 1024, 0, stream>>>(y_h, b_d1, W_d2, b_d2, W_fc, b_fc,
                                      Wih_d, bih_d, bhh_d, W_ff, b_ff, ws, out);
}

// Round 14
// 9112.444 us; speedup vs baseline: 1.9091x; 1.0393x over previous
//
#include <hip/hip_runtime.h>
#include <hip/hip_bf16.h>
#include <hip/hip_fp16.h>

#define BB  512
#define TT  256
#define MM  81
#define HEE 256

// ---- workspace layout (float offsets) ----
#define OFF_W8AH   0          // uint4[64 k8][256 j]   encoder p1, 8 halves (k over [h;c])
#define OFF_WE8    65536      // uint4[169 k2][256 j]  encoder LSTM, gate-major pairs
#define OFF_W8D1   238592     // uint4[64 k8][256 j]   decoder p1, 8 halves
#define OFF_WD8G   304128     // uint4[4 gate][32 k8][256 j] decoder Whh per-gate
#define OFF_ATTN   436224     // [512][81] attn_in
#define OFF_ENCW   477696     // [512][256] enc . W_fc[:256]
#define OFF_ENC    608768     // [512][256][256] input_encoded fp32
#define OFF_EPI    34163200   // half[512 b][256 t'][256 h] enc_proj (fp16 master)
#define WS_FLOATS  50940416

typedef _Float16 hh2 __attribute__((ext_vector_type(2)));

__device__ __forceinline__ float frcp(float x) { return __builtin_amdgcn_rcpf(x); }
__device__ __forceinline__ float fsig(float x) { return frcp(1.f + __expf(-x)); }
__device__ __forceinline__ float ftanh(float x) { return 1.f - 2.f * frcp(__expf(2.f * x) + 1.f); }
// tanh building block: tanh(x) = 1 - 2*rr(x), rr(x) = 1/(exp(2x)+1)
__device__ __forceinline__ float rrf(float x) { return frcp(__expf(2.f * x) + 1.f); }
__device__ __forceinline__ hh2 uash2(unsigned int u) { union { unsigned int u; hh2 h; } x; x.u = u; return x.h; }
__device__ __forceinline__ float fdot2f(unsigned int a, unsigned int b, float c) {
#if __has_builtin(__builtin_amdgcn_fdot2)
  return __builtin_amdgcn_fdot2(uash2(a), uash2(b), c, false);
#else
  hh2 ha = uash2(a), hb = uash2(b);
  return c + (float)ha.x * (float)hb.x + (float)ha.y * (float)hb.y;
#endif
}
__device__ __forceinline__ ushort f2h(float x) { return __half_as_ushort(__float2half(x)); }

// ---- fp8 e4m3 helpers (HW builtins; self-consistent SW fallback) ----
#if __has_builtin(__builtin_amdgcn_cvt_pk_f32_fp8) && __has_builtin(__builtin_amdgcn_cvt_pk_fp8_f32)
typedef float ff2 __attribute__((ext_vector_type(2)));
__device__ __forceinline__ float2 cvt2lo(unsigned v) { ff2 r = __builtin_amdgcn_cvt_pk_f32_fp8(v, false); return make_float2(r[0], r[1]); }
__device__ __forceinline__ float2 cvt2hi(unsigned v) { ff2 r = __builtin_amdgcn_cvt_pk_f32_fp8(v, true);  return make_float2(r[0], r[1]); }
__device__ __forceinline__ unsigned pk4_fp8(unsigned a, unsigned b) {
  float2 fa = __half22float2(*(__half2*)&a);
  float2 fb = __half22float2(*(__half2*)&b);
  int r = __builtin_amdgcn_cvt_pk_fp8_f32(fa.x, fa.y, 0, false);
  r = __builtin_amdgcn_cvt_pk_fp8_f32(fb.x, fb.y, r, true);
  return (unsigned)r;
}
#else
__device__ __forceinline__ float dec1_fp8(unsigned b) {
  unsigned s = b >> 7, ef = (b >> 3) & 0xf, m = b & 7;
  float v = (ef == 0) ? (float)m * 0.001953125f
                      : (1.f + (float)m * 0.125f) * exp2f((float)((int)ef - 7));
  return s ? -v : v;
}
__device__ __forceinline__ float2 cvt2lo(unsigned v) { return make_float2(dec1_fp8(v & 0xff), dec1_fp8((v >> 8) & 0xff)); }
__device__ __forceinline__ float2 cvt2hi(unsigned v) { return make_float2(dec1_fp8((v >> 16) & 0xff), dec1_fp8((v >> 24) & 0xff)); }
__device__ __forceinline__ unsigned enc1_fp8(float x) {
  unsigned u = __float_as_uint(x); unsigned sgn = (u >> 31) << 7;
  float ax = fabsf(x);
  if (ax < 0.0009765625f) return sgn;
  if (ax >= 448.f) return sgn | 0x7e;
  if (ax < 0.015625f) { int k = (int)rintf(ax * 512.f); return (k >= 8) ? (sgn | 0x08) : (sgn | (unsigned)k); }
  int e = (int)((u >> 23) & 0xff) - 127;
  unsigned m = u & 0x7fffff;
  unsigned mr = m + 0x7ffff + ((m >> 20) & 1);
  if (mr >= 0x800000) { mr = 0; ++e; if (e > 8) return sgn | 0x7e; }
  return sgn | (unsigned)((e + 7) << 3) | (mr >> 20);
}
__device__ __forceinline__ unsigned pk4_fp8(unsigned a, unsigned b) {
  float2 fa = __half22float2(*(__half2*)&a);
  float2 fb = __half22float2(*(__half2*)&b);
  return enc1_fp8(fa.x) | (enc1_fp8(fa.y) << 8) | (enc1_fp8(fb.x) << 16) | (enc1_fp8(fb.y) << 24);
}
#endif

// ---------------- weight prep (layouts unchanged from R13) ----------------
__global__ void k_prep(const float* __restrict__ W_ah, const float* __restrict__ Wih_e,
                       const float* __restrict__ Whh_e, const float* __restrict__ W_d1,
                       const float* __restrict__ Wih_d, const float* __restrict__ Whh_d,
                       float* __restrict__ ws) {
  int idx = blockIdx.x * 512 + threadIdx.x;
  if (idx < 16384) {
    int k8 = idx >> 8, j = idx & 255;
    const float* wr = W_ah + (size_t)j * 512 + 8 * k8;
    union { __half2 h[4]; uint4 u; } w;
    w.h[0] = __floats2half2_rn(wr[0], wr[1]);
    w.h[1] = __floats2half2_rn(wr[2], wr[3]);
    w.h[2] = __floats2half2_rn(wr[4], wr[5]);
    w.h[3] = __floats2half2_rn(wr[6], wr[7]);
    ((uint4*)(ws + OFF_W8AH))[idx] = w.u;
  }
  if (idx < 16384) {
    int k8 = idx >> 8, j = idx & 255;
    const float* wr = W_d1 + (size_t)j * 768 + 8 * k8;
    union { __half2 h[4]; uint4 u; } w;
    w.h[0] = __floats2half2_rn(wr[0], wr[1]);
    w.h[1] = __floats2half2_rn(wr[2], wr[3]);
    w.h[2] = __floats2half2_rn(wr[4], wr[5]);
    w.h[3] = __floats2half2_rn(wr[6], wr[7]);
    ((uint4*)(ws + OFF_W8D1))[idx] = w.u;
  }
  if (idx < 43264) {
    int k2 = idx >> 8, j = idx & 255;
    auto we = [&](int g, int kk) -> float {
      if (kk < 81)  return Wih_e[(g * 256 + j) * 81 + kk];
      if (kk < 337) return Whh_e[(g * 256 + j) * 256 + (kk - 81)];
      return 0.f;
    };
    int ke = 2 * k2, ko = 2 * k2 + 1;
    union { __half2 h[4]; uint4 u; } w;
    w.h[0] = __floats2half2_rn(we(0, ke), we(0, ko));
    w.h[1] = __floats2half2_rn(we(1, ke), we(1, ko));
    w.h[2] = __floats2half2_rn(we(2, ke), we(2, ko));
    w.h[3] = __floats2half2_rn(we(3, ke), we(3, ko));
    ((uint4*)(ws + OFF_WE8))[idx] = w.u;
  }
  if (idx < 32768) {
    int r = idx >> 8, j = idx & 255;
    int gate = r >> 5, k8 = r & 31;
    const float* wr = Whh_d + (size_t)(gate * 256 + j) * 256 + 8 * k8;
    union { __half2 h[4]; uint4 u; } w;
    w.h[0] = __floats2half2_rn(wr[0], wr[1]);
    w.h[1] = __floats2half2_rn(wr[2], wr[3]);
    w.h[2] = __floats2half2_rn(wr[4], wr[5]);
    w.h[3] = __floats2half2_rn(wr[6], wr[7]);
    ((uint4*)(ws + OFF_WD8G))[idx] = w.u;
  }
}

// ---------------- attn_in[b][m] ----------------
__global__ void k_attn(const float* __restrict__ x, const float* __restrict__ W_ai,
                       const float* __restrict__ b_ai, float* __restrict__ ws) {
  __shared__ float wai[256];
  const int b = blockIdx.x, tid = threadIdx.x;  // 128 threads
  wai[tid] = W_ai[tid];
  wai[128 + tid] = W_ai[128 + tid];
  __syncthreads();
  if (tid < MM) {
    float acc = b_ai[0];
    const float* xp = x + (size_t)b * TT * MM + tid;
    #pragma unroll 8
    for (int t = 0; t < TT; ++t) acc = fmaf(xp[t * MM], wai[t], acc);
    ws[OFF_ATTN + b * MM + tid] = acc;
  }
}

// ---------------- encoder: 1024 threads, 2 batch rows, 256 steps ----------------
__global__ __launch_bounds__(1024, 2) void k_encoder(
    const float* __restrict__ x, const float* __restrict__ b_ah,
    const float* __restrict__ W_a, const float* __restrict__ b_a,
    const float* __restrict__ bih_e, const float* __restrict__ bhh_e,
    float* __restrict__ ws) {
  __shared__ __align__(16) float aA[2048];
  __shared__ __align__(16) float4 gA[2048];
  __shared__ __align__(16) float hpb[512];
  __shared__ __align__(16) float wa2m[256];    // -2*W_a
  __shared__ __align__(16) ushort hcb[2][512];
  __shared__ __align__(16) ushort uu[2][344];
  const int tid = threadIdx.x;
  const int j = tid & 255, q = tid >> 8;
  const int b0 = blockIdx.x * 2, b1 = b0 + 1;

  if (tid < 256) wa2m[tid] = -2.f * W_a[tid];
  if (tid < 512) { hcb[0][tid] = 0; hcb[1][tid] = 0; }
  if (tid < 344) { uu[0][tid] = 0; uu[1][tid] = 0; }
  float bahr = 0.f; float4 bias4 = {0, 0, 0, 0};
  if (tid < 512) {
    bahr = b_ah[j];
    bias4.x = bih_e[j] + bhh_e[j];
    bias4.y = bih_e[256 + j] + bhh_e[256 + j];
    bias4.z = bih_e[512 + j] + bhh_e[512 + j];
    bias4.w = bih_e[768 + j] + bhh_e[768 + j];
  }
  float ai0 = 0.f, ai1 = 0.f;
  {
    int m = tid & 127;
    if (m < MM) {
      ai0 = ws[OFF_ATTN + b0 * MM + m];
      ai1 = ws[OFF_ATTN + b1 * MM + m];
    }
  }
  const float bav = b_a[0];
  float xc0 = 0.f, xc1 = 0.f;
  if (tid < 128) {
    int bb = (tid >= 64) ? b1 : b0;
    int lane = tid & 63;
    xc0 = x[((size_t)bb * TT) * MM + lane];
    xc1 = (lane < 17) ? x[((size_t)bb * TT) * MM + 64 + lane] : 0.f;
  }
  const uint4* __restrict__ W8A = (const uint4*)(ws + OFF_W8AH);
  const uint4* __restrict__ We8 = (const uint4*)(ws + OFF_WE8);
  const uint4* __restrict__ hcq0 = (const uint4*)hcb[0];
  const uint4* __restrict__ hcq1 = (const uint4*)hcb[1];
  const unsigned int* __restrict__ u0p = (const unsigned int*)uu[0];
  const unsigned int* __restrict__ u1p = (const unsigned int*)uu[1];
  float creg = 0.f;
  __syncthreads();
  // bavw = b_a + sum_t W_a  (constant fold of the -2 trick)
  float bavw = bav;
  if (tid < 128) {
    float s = 0.f;
    #pragma unroll
    for (int i = 0; i < 64; ++i) {
      float4 v = *(const float4*)&wa2m[4 * i];
      s += v.x + v.y + v.z + v.w;
    }
    bavw = bav - 0.5f * s;
  }

  for (int t = 0; t < TT; ++t) {
    // ---- A: p1 partials (split accumulators) + LSTM h-part partials ----
    {
      float a0 = 0.f, a0b = 0.f, a1 = 0.f, a1b = 0.f;
      const int k8b = q * 16;
      #pragma unroll 4
      for (int i = 0; i < 16; ++i) {
        int k8 = k8b + i;
        uint4 wu = W8A[k8 * 256 + j];
        uint4 h0 = hcq0[k8], h1 = hcq1[k8];
        a0  = fdot2f(wu.x, h0.x, a0);  a0b = fdot2f(wu.y, h0.y, a0b);
        a0  = fdot2f(wu.z, h0.z, a0);  a0b = fdot2f(wu.w, h0.w, a0b);
        a1  = fdot2f(wu.x, h1.x, a1);  a1b = fdot2f(wu.y, h1.y, a1b);
        a1  = fdot2f(wu.z, h1.z, a1);  a1b = fdot2f(wu.w, h1.w, a1b);
      }
      aA[(q * 256 + j) * 2 + 0] = a0 + a0b;
      aA[(q * 256 + j) * 2 + 1] = a1 + a1b;
      float4 g0 = {0, 0, 0, 0}, g1 = {0, 0, 0, 0};
      const int ku0 = 41 + q * 32;
      #pragma unroll 4
      for (int i = 0; i < 32; ++i) {
        int ku = ku0 + i;
        uint4 wu = We8[ku * 256 + j];
        unsigned int ua = u0p[ku], ub = u1p[ku];
        g0.x = fdot2f(wu.x, ua, g0.x); g0.y = fdot2f(wu.y, ua, g0.y);
        g0.z = fdot2f(wu.z, ua, g0.z); g0.w = fdot2f(wu.w, ua, g0.w);
        g1.x = fdot2f(wu.x, ub, g1.x); g1.y = fdot2f(wu.y, ub, g1.y);
        g1.z = fdot2f(wu.z, ub, g1.z); g1.w = fdot2f(wu.w, ub, g1.w);
      }
      gA[(q * 2 + 0) * 256 + j] = g0;
      gA[(q * 2 + 1) * 256 + j] = g1;
    }
    __syncthreads();
    if (tid < 512) {
      int b = tid >> 8, h = tid & 255;
      hpb[2 * h + b] = aA[(0 * 256 + h) * 2 + b] + aA[(1 * 256 + h) * 2 + b] +
                       aA[(2 * 256 + h) * 2 + b] + aA[(3 * 256 + h) * 2 + b] + bahr;
    }
    __syncthreads();
    // ---- C: score[m] partials via -2w*rr with split accumulators ----
    {
      int m = tid & 127, tq = tid >> 7;
      if (m < MM) {
        float e0a = 0.f, e0b = 0.f, e1a = 0.f, e1b = 0.f;
        #pragma unroll 4
        for (int i = tq * 16; i < tq * 16 + 16; ++i) {
          float4 hv = *(const float4*)&hpb[i * 4];
          float2 wv = *(const float2*)&wa2m[i * 2];
          e0a = fmaf(wv.x, rrf(hv.x + ai0), e0a);
          e0b = fmaf(wv.y, rrf(hv.z + ai0), e0b);
          e1a = fmaf(wv.x, rrf(hv.y + ai1), e1a);
          e1b = fmaf(wv.y, rrf(hv.w + ai1), e1b);
        }
        aA[(tq * 2 + 0) * 96 + m] = e0a + e0b;
        aA[(tq * 2 + 1) * 96 + m] = e1a + e1b;
      }
    }
    __syncthreads();
    // ---- D: softmax over m + wi fp16 writes ----
    if (tid < 128) {
      int wv_id = tid >> 6, lane = tid & 63;
      float v0 = bavw, v1 = bavw;
      #pragma unroll
      for (int tq = 0; tq < 8; ++tq) {
        v0 += aA[(tq * 2 + wv_id) * 96 + lane];
        if (lane < 17) v1 += aA[(tq * 2 + wv_id) * 96 + 64 + lane];
      }
      float e0 = __expf(v0);
      float e1 = (lane < 17) ? __expf(v1) : 0.f;
      float sm = e0 + e1;
      #pragma unroll
      for (int d = 1; d < 64; d <<= 1) sm += __shfl_xor(sm, d);
      float inv = frcp(sm);
      uu[wv_id][lane] = f2h(e0 * inv * xc0);
      if (lane < 17) uu[wv_id][64 + lane] = f2h(e1 * inv * xc1);
      if (t < 255) {
        int bb = wv_id ? b1 : b0;
        xc0 = x[((size_t)bb * TT + t + 1) * MM + lane];
        xc1 = (lane < 17) ? x[((size_t)bb * TT + t + 1) * MM + 64 + lane] : 0.f;
      }
    }
    __syncthreads();
    // ---- E: LSTM wi-part partials ----
    {
      const int kA = (q == 0) ? 0 : (q == 1) ? 11 : (q == 2) ? 21 : 31;
      const int kB = (q == 0) ? 11 : (q == 1) ? 21 : (q == 2) ? 31 : 41;
      float4 g0 = gA[(q * 2 + 0) * 256 + j];
      float4 g1 = gA[(q * 2 + 1) * 256 + j];
      for (int ku = kA; ku < kB; ++ku) {
        uint4 wu = We8[ku * 256 + j];
        unsigned int ua = u0p[ku], ub = u1p[ku];
        g0.x = fdot2f(wu.x, ua, g0.x); g0.y = fdot2f(wu.y, ua, g0.y);
        g0.z = fdot2f(wu.z, ua, g0.z); g0.w = fdot2f(wu.w, ua, g0.w);
        g1.x = fdot2f(wu.x, ub, g1.x); g1.y = fdot2f(wu.y, ub, g1.y);
        g1.z = fdot2f(wu.z, ub, g1.z); g1.w = fdot2f(wu.w, ub, g1.w);
      }
      gA[(q * 2 + 0) * 256 + j] = g0;
      gA[(q * 2 + 1) * 256 + j] = g1;
    }
    __syncthreads();
    // ---- F: gate combine + state update ----
    if (tid < 512) {
      int b = tid >> 8, jj = tid & 255;
      float4 s0 = gA[(0 * 2 + b) * 256 + jj];
      float4 s1 = gA[(1 * 2 + b) * 256 + jj];
      float4 s2 = gA[(2 * 2 + b) * 256 + jj];
      float4 s3 = gA[(3 * 2 + b) * 256 + jj];
      float gi = s0.x + s1.x + s2.x + s3.x + bias4.x;
      float gf = s0.y + s1.y + s2.y + s3.y + bias4.y;
      float gg = s0.z + s1.z + s2.z + s3.z + bias4.z;
      float go = s0.w + s1.w + s2.w + s3.w + bias4.w;
      float c = fsig(gf) * creg + fsig(gi) * ftanh(gg);
      float h = fsig(go) * ftanh(c);
      creg = c;
      hcb[b][jj] = f2h(h);
      hcb[b][256 + jj] = f2h(c);
      uu[b][81 + jj] = f2h(h);
      ws[OFF_ENC + (((size_t)(b ? b1 : b0) * TT + t) * HEE + jj)] = h;
    }
    __syncthreads();
  }
}

// ---------------- encW[b][t] = enc[b,t,:] . W_fc[:256] ----------------
__global__ __launch_bounds__(256) void k_encw(const float* __restrict__ W_fc, float* __restrict__ ws) {
  const float* __restrict__ enc = ws + OFF_ENC;
  const int wv = threadIdx.x >> 6, lane = threadIdx.x & 63;
  float4 wfc = reinterpret_cast<const float4*>(W_fc)[lane];
  for (int r = blockIdx.x * 4 + wv; r < BB * TT; r += 4096) {
    float4 e = reinterpret_cast<const float4*>(enc + (size_t)r * HEE)[lane];
    float d = e.x * wfc.x + e.y * wfc.y + e.z * wfc.z + e.w * wfc.w;
    #pragma unroll
    for (int dd = 1; dd < 64; dd <<= 1) d += __shfl_xor(d, dd);
    if (lane == 0) ws[OFF_ENCW + r] = d;
  }
}

// ---------------- enc_proj fp16: epH[b][t'][h] ----------------
__global__ __launch_bounds__(256) void k_encproj(const float* __restrict__ W_d1, float* __restrict__ ws) {
  __shared__ __align__(16) float le[16][256];
  const int tid = threadIdx.x;
  const int b = blockIdx.x >> 4;
  const int t0 = (blockIdx.x & 15) * 16;
  const float* __restrict__ enc = ws + OFF_ENC;
  __half* __restrict__ epH = (__half*)(ws + OFF_EPI);
  #pragma unroll
  for (int rr = 0; rr < 16; ++rr)
    le[rr][tid] = enc[((size_t)b * TT + (t0 + rr)) * HEE + tid];
  __syncthreads();
  const float4* wrow = (const float4*)(W_d1 + (size_t)tid * 768 + 512);
  float acc[16];
  #pragma unroll
  for (int r = 0; r < 16; ++r) acc[r] = 0.f;
  for (int e4 = 0; e4 < 64; ++e4) {
    float4 w = wrow[e4];
    #pragma unroll
    for (int r = 0; r < 16; ++r) {
      float4 ev = *(const float4*)&le[r][e4 * 4];
      acc[r] += ev.x * w.x + ev.y * w.y + ev.z * w.z + ev.w * w.w;
    }
  }
  #pragma unroll
  for (int rr = 0; rr < 16; ++rr)
    epH[((size_t)b * TT + (t0 + rr)) * HEE + tid] = __float2half(acc[rr]);
}

// ---------------- decoder: 512 WGs x 1024 threads, 1 batch/WG, 2 WGs/CU ----------------
__global__ __launch_bounds__(1024, 8) void k_decoder(
    const float* __restrict__ y_history, const float* __restrict__ b_d1,
    const float* __restrict__ W_d2, const float* __restrict__ b_d2,
    const float* __restrict__ W_fc, const float* __restrict__ b_fc,
    const float* __restrict__ Wih_d,
    const float* __restrict__ bih_d, const float* __restrict__ bhh_d,
    const float* __restrict__ W_ff, const float* __restrict__ b_ff,
    float* __restrict__ ws, float* __restrict__ out) {
  __shared__ __align__(16) unsigned char ep8L[65536]; // fp8 ep, swizzled (64 KB)
  __shared__ __align__(16) float aA[1024];
  __shared__ __align__(16) float gL[1024];
  __shared__ __align__(16) float ddp[256];
  __shared__ __align__(16) ushort hc[512];
  __shared__ __align__(16) float w2m[256];     // -2*W_d2
  __shared__ __align__(16) float ybuf[256];
  __shared__ float red[2][4];
  const int tid = threadIdx.x;
  const int tp = tid & 255, q = tid >> 8;
  const int lane = tid & 63, wvid = tid >> 6;
  const int b = blockIdx.x;
  const float wfcy = W_fc[256], bfc = b_fc[0], bd2v = b_d2[0], bffv = b_ff[0];

  if (tid < 256) w2m[tid] = -2.f * W_d2[tid];
  if (tid < 512) hc[tid] = 0;
  if (tid < 255) ybuf[tid] = y_history[(size_t)b * 255 + tid] * wfcy + bfc;
  const float bd1r = b_d1[tp];
  float4 biasd, wy;
  biasd.x = bih_d[tp] + bhh_d[tp];
  biasd.y = bih_d[256 + tp] + bhh_d[256 + tp];
  biasd.z = bih_d[512 + tp] + bhh_d[512 + tp];
  biasd.w = bih_d[768 + tp] + bhh_d[768 + tp];
  wy.x = Wih_d[tp]; wy.y = Wih_d[256 + tp]; wy.z = Wih_d[512 + tp]; wy.w = Wih_d[768 + tp];
  const float wffh = W_ff[tp], wffc = W_ff[256 + tp];
  const float ewr = ws[OFF_ENCW + (size_t)b * 256 + tp];

  const uint4* __restrict__ W8 = (const uint4*)(ws + OFF_W8D1);
  const uint4* __restrict__ WG = (const uint4*)(ws + OFF_WD8G);
  const uint4* __restrict__ epg = (const uint4*)(ws + OFF_EPI);
  const uint4* __restrict__ ep16 = (const uint4*)ep8L;
  const uint4* __restrict__ hc4 = (const uint4*)hc;

  {
    #pragma unroll
    for (int k = 0; k < 4; ++k) {
      int g = k * 1024 + tid;
      int t = g >> 4, c = g & 15;
      const uint4* src = epg + (size_t)b * 8192 + t * 32 + c * 2;
      uint4 lo = src[0], hi = src[1];
      uint4 o;
      o.x = pk4_fp8(lo.x, lo.y);
      o.y = pk4_fp8(lo.z, lo.w);
      o.z = pk4_fp8(hi.x, hi.y);
      o.w = pk4_fp8(hi.z, hi.w);
      ((uint4*)ep8L)[(g & ~15) | (c ^ (t & 15))] = o;
    }
  }
  const uint4* __restrict__ epXg = epg + (size_t)b * 8192 + tp * 32 + q * 8;
  __syncthreads();
  // bd2w = b_d2 + sum_h W_d2 (constant fold of -2 trick)
  float bd2w = bd2v;
  if (tid < 256) {
    float s = 0.f;
    #pragma unroll
    for (int i = 0; i < 64; ++i) {
      float4 v = *(const float4*)&w2m[4 * i];
      s += v.x + v.y + v.z + v.w;
    }
    bd2w = bd2v - 0.5f * s;
  }

  float hreg = 0.f, creg = 0.f;
  float escls = 0.f, invls = 0.f, esc = 0.f;

  for (int s = 0; s < 255; ++s) {
    // ---- A: p1 partial (4 acc chains) + one full gate per thread (4 acc chains) ----
    {
      float a0 = 0.f, a1 = 0.f, a2 = 0.f, a3 = 0.f;
      const int k8b = q * 16;
      #pragma unroll 4
      for (int i = 0; i < 16; ++i) {
        int k8 = k8b + i;
        uint4 wu = W8[k8 * 256 + tp];
        uint4 hv = hc4[k8];
        a0 = fdot2f(wu.x, hv.x, a0); a1 = fdot2f(wu.y, hv.y, a1);
        a2 = fdot2f(wu.z, hv.z, a2); a3 = fdot2f(wu.w, hv.w, a3);
      }
      aA[q * 256 + tp] = (a0 + a1) + (a2 + a3);
      float g0 = 0.f, g1 = 0.f, g2 = 0.f, g3 = 0.f;
      const uint4* wg = WG + (q * 32) * 256 + tp;
      #pragma unroll 4
      for (int i = 0; i < 32; ++i) {
        uint4 wu = wg[i * 256];
        uint4 hv = hc4[i];
        g0 = fdot2f(wu.x, hv.x, g0); g1 = fdot2f(wu.y, hv.y, g1);
        g2 = fdot2f(wu.z, hv.z, g2); g3 = fdot2f(wu.w, hv.w, g3);
      }
      gL[q * 256 + tp] = (g0 + g1) + (g2 + g3);
    }
    __syncthreads();
    // ---- B: d combine ----
    if (tid < 256)
      ddp[tid] = aA[tid] + aA[256 + tid] + aA[512 + tid] + aA[768 + tid] + bd1r;
    __syncthreads();
    // ---- C: score partials via -2w*rr (2 acc chains); exact fp16 at s==254 ----
    if (s != 254) {
      float q0 = 0.f, q1 = 0.f;
      const int base = tp * 16, sw = tp & 15;
      #pragma unroll
      for (int k = 0; k < 4; ++k) {
        uint4 eu = ep16[base + ((q * 4 + k) ^ sw)];
        const int hb = q * 64 + k * 16;
        const unsigned* ed = (const unsigned*)&eu;
        #pragma unroll
        for (int dd = 0; dd < 4; ++dd) {
          const int h4 = hb + dd * 4;
          float2 xa = cvt2lo(ed[dd]), xb = cvt2hi(ed[dd]);
          float4 wf = *(const float4*)&w2m[h4];
          float4 dv = *(const float4*)&ddp[h4];
          q0 = fmaf(wf.x, rrf(xa.x + dv.x), q0);
          q1 = fmaf(wf.y, rrf(xa.y + dv.y), q1);
          q0 = fmaf(wf.z, rrf(xb.x + dv.z), q0);
          q1 = fmaf(wf.w, rrf(xb.y + dv.w), q1);
        }
      }
      aA[q * 256 + tp] = q0 + q1;
    } else {
      float q0 = 0.f, q1 = 0.f;
      #pragma unroll
      for (int k = 0; k < 8; ++k) {
        uint4 eu = epXg[k];
        const int h8 = q * 64 + k * 8;
        const __half2* eh = (const __half2*)&eu;
        #pragma unroll
        for (int jj = 0; jj < 4; ++jj) {
          float2 ea = __half22float2(eh[jj]);
          float2 wf = *(const float2*)&w2m[h8 + 2 * jj];
          float2 dv = *(const float2*)&ddp[h8 + 2 * jj];
          q0 = fmaf(wf.x, rrf(ea.x + dv.x), q0);
          q1 = fmaf(wf.y, rrf(ea.y + dv.y), q1);
        }
      }
      aA[q * 256 + tp] = q0 + q1;
    }
    __syncthreads();
    // ---- D: softmax partial reductions (no max-shift) ----
    if (tid < 256) {
      float v = aA[tp] + aA[256 + tp] + aA[512 + tp] + aA[768 + tp] + bd2w;
      esc = __expf(v);
      float den = esc, num = esc * ewr;
      #pragma unroll
      for (int d = 1; d < 64; d <<= 1) { den += __shfl_xor(den, d); num += __shfl_xor(num, d); }
      if (lane == 0) { red[0][wvid] = den; red[1][wvid] = num; }
    }
    __syncthreads();
    // ---- E: y + gate combine + state update ----
    if (tid < 256) {
      float den = red[0][0] + red[0][1] + red[0][2] + red[0][3];
      float num = red[1][0] + red[1][1] + red[1][2] + red[1][3];
      float inv = frcp(den);
      float y = num * inv + ybuf[s];
      if (s == 254) { escls = esc; invls = inv; }
      float gi = gL[tp]       + wy.x * y + biasd.x;
      float gf = gL[256 + tp] + wy.y * y + biasd.y;
      float gg = gL[512 + tp] + wy.z * y + biasd.z;
      float go = gL[768 + tp] + wy.w * y + biasd.w;
      float c = fsig(gf) * creg + fsig(gi) * ftanh(gg);
      float h = fsig(go) * ftanh(c);
      creg = c; hreg = h;
      hc[tp] = f2h(h);
      hc[256 + tp] = f2h(c);
    }
    __syncthreads();
  }

  // ---- finale: last-step aw + ctx + output ----
  if (tid < 256) ddp[tp] = escls * invls;
  __syncthreads();
  {
    float c0 = 0.f;
    const float* __restrict__ e32 = ws + OFF_ENC + (size_t)b * TT * HEE;
    for (int t = q * 64; t < q * 64 + 64; ++t)
      c0 = fmaf(ddp[t], e32[(size_t)t * HEE + tp], c0);
    __syncthreads();
    aA[q * 256 + tp] = c0;
  }
  __syncthreads();
  if (tid < 256) {
    float ctx = aA[tp] + aA[256 + tp] + aA[512 + tp] + aA[768 + tp];
    float p = hreg * wffh + ctx * wffc;
    #pragma unroll
    for (int d = 1; d < 64; d <<= 1) p += __shfl_xor(p, d);
    if (lane == 0) red[0][wvid] = p;
  }
  __syncthreads();
  if (tid == 0) out[b] = red[0][0] + red[0][1] + red[0][2] + red[0][3] + bffv;
}

extern "C" void kernel_launch(void* const* d_in, const int* in_sizes, int n_in,
                              void* d_out, int out_size, void* d_ws, size_t ws_size,
                              hipStream_t stream) {
  if (ws_size < (size_t)WS_FLOATS * sizeof(float)) return;
  const float* x     = (const float*)d_in[0];
  const float* y_h   = (const float*)d_in[1];
  const float* W_ah  = (const float*)d_in[2];
  const float* b_ah  = (const float*)d_in[3];
  const float* W_ai  = (const float*)d_in[4];
  const float* b_ai  = (const float*)d_in[5];
  const float* W_a   = (const float*)d_in[6];
  const float* b_a   = (const float*)d_in[7];
  const float* Wih_e = (const float*)d_in[8];
  const float* Whh_e = (const float*)d_in[9];
  const float* bih_e = (const float*)d_in[10];
  const float* bhh_e = (const float*)d_in[11];
  const float* W_d1  = (const float*)d_in[12];
  const float* b_d1  = (const float*)d_in[13];
  const float* W_d2  = (const float*)d_in[14];
  const float* b_d2  = (const float*)d_in[15];
  const float* W_fc  = (const float*)d_in[16];
  const float* b_fc  = (const float*)d_in[17];
  const float* Wih_d = (const float*)d_in[18];
  const float* Whh_d = (const float*)d_in[19];
  const float* bih_d = (const float*)d_in[20];
  const float* bhh_d = (const float*)d_in[21];
  const float* W_ff  = (const float*)d_in[22];
  const float* b_ff  = (const float*)d_in[23];
  float* ws  = (float*)d_ws;
  float* out = (float*)d_out;

  k_prep<<<256, 512, 0, stream>>>(W_ah, Wih_e, Whh_e, W_d1, Wih_d, Whh_d, ws);
  k_attn<<<512, 128, 0, stream>>>(x, W_ai, b_ai, ws);
  k_encoder<<<256, 1024, 0, stream>>>(x, b_ah, W_a, b_a, bih_e, bhh_e, ws);
  k_encw<<<1024, 256, 0, stream>>>(W_fc, ws);
  k_encproj<<<8192, 256, 0, stream>>>(W_d1, ws);
  k_decoder<<<512, 1024, 0, stream>>>(y_h, b_d1, W_d2, b_d2, W_fc, b_fc,
                                      Wih_d, bih_d, bhh_d, W_ff, b_ff, ws, out);
}

// Round 15
// 9093.159 us; speedup vs baseline: 1.9131x; 1.0021x over previous
//
#include <hip/hip_runtime.h>
#include <hip/hip_bf16.h>
#include <hip/hip_fp16.h>

#define BB  512
#define TT  256
#define MM  81
#define HEE 256

// ---- workspace layout (float offsets) ----
#define OFF_W8AH   0          // uint4[64 k8][256 j]   encoder p1, 8 halves (k over [h;c])
#define OFF_WE8    65536      // uint4[169 k2][256 j]  encoder LSTM, gate-major pairs
#define OFF_W8D1   238592     // uint4[64 k8][256 j]   decoder p1, 8 halves
#define OFF_WD8G   304128     // uint4[4 gate][32 k8][256 j] decoder Whh per-gate
#define OFF_ATTN   436224     // [512][81] attn_in
#define OFF_ENCW   477696     // [512][256] enc . W_fc[:256]
#define OFF_ENC    608768     // [512][256][256] input_encoded fp32
#define OFF_EPI    34163200   // half[512 b][256 t'][256 h] enc_proj (fp16 master)
#define WS_FLOATS  50940416

typedef _Float16 hh2 __attribute__((ext_vector_type(2)));

__device__ __forceinline__ float frcp(float x) { return __builtin_amdgcn_rcpf(x); }
__device__ __forceinline__ float fsig(float x) { return frcp(1.f + __expf(-x)); }
__device__ __forceinline__ float ftanh(float x) { return 1.f - 2.f * frcp(__expf(2.f * x) + 1.f); }
// tanh building block: tanh(x) = 1 - 2*rr(x), rr(x) = 1/(exp(2x)+1)
__device__ __forceinline__ float rrf(float x) { return frcp(__expf(2.f * x) + 1.f); }
__device__ __forceinline__ hh2 uash2(unsigned int u) { union { unsigned int u; hh2 h; } x; x.u = u; return x.h; }
__device__ __forceinline__ float fdot2f(unsigned int a, unsigned int b, float c) {
#if __has_builtin(__builtin_amdgcn_fdot2)
  return __builtin_amdgcn_fdot2(uash2(a), uash2(b), c, false);
#else
  hh2 ha = uash2(a), hb = uash2(b);
  return c + (float)ha.x * (float)hb.x + (float)ha.y * (float)hb.y;
#endif
}
__device__ __forceinline__ ushort f2h(float x) { return __half_as_ushort(__float2half(x)); }

// ---- fp8 e4m3 helpers (HW builtins; self-consistent SW fallback) ----
#if __has_builtin(__builtin_amdgcn_cvt_pk_f32_fp8) && __has_builtin(__builtin_amdgcn_cvt_pk_fp8_f32)
typedef float ff2 __attribute__((ext_vector_type(2)));
__device__ __forceinline__ float2 cvt2lo(unsigned v) { ff2 r = __builtin_amdgcn_cvt_pk_f32_fp8(v, false); return make_float2(r[0], r[1]); }
__device__ __forceinline__ float2 cvt2hi(unsigned v) { ff2 r = __builtin_amdgcn_cvt_pk_f32_fp8(v, true);  return make_float2(r[0], r[1]); }
__device__ __forceinline__ unsigned pk4_fp8(unsigned a, unsigned b) {
  float2 fa = __half22float2(*(__half2*)&a);
  float2 fb = __half22float2(*(__half2*)&b);
  int r = __builtin_amdgcn_cvt_pk_fp8_f32(fa.x, fa.y, 0, false);
  r = __builtin_amdgcn_cvt_pk_fp8_f32(fb.x, fb.y, r, true);
  return (unsigned)r;
}
#else
__device__ __forceinline__ float dec1_fp8(unsigned b) {
  unsigned s = b >> 7, ef = (b >> 3) & 0xf, m = b & 7;
  float v = (ef == 0) ? (float)m * 0.001953125f
                      : (1.f + (float)m * 0.125f) * exp2f((float)((int)ef - 7));
  return s ? -v : v;
}
__device__ __forceinline__ float2 cvt2lo(unsigned v) { return make_float2(dec1_fp8(v & 0xff), dec1_fp8((v >> 8) & 0xff)); }
__device__ __forceinline__ float2 cvt2hi(unsigned v) { return make_float2(dec1_fp8((v >> 16) & 0xff), dec1_fp8((v >> 24) & 0xff)); }
__device__ __forceinline__ unsigned enc1_fp8(float x) {
  unsigned u = __float_as_uint(x); unsigned sgn = (u >> 31) << 7;
  float ax = fabsf(x);
  if (ax < 0.0009765625f) return sgn;
  if (ax >= 448.f) return sgn | 0x7e;
  if (ax < 0.015625f) { int k = (int)rintf(ax * 512.f); return (k >= 8) ? (sgn | 0x08) : (sgn | (unsigned)k); }
  int e = (int)((u >> 23) & 0xff) - 127;
  unsigned m = u & 0x7fffff;
  unsigned mr = m + 0x7ffff + ((m >> 20) & 1);
  if (mr >= 0x800000) { mr = 0; ++e; if (e > 8) return sgn | 0x7e; }
  return sgn | (unsigned)((e + 7) << 3) | (mr >> 20);
}
__device__ __forceinline__ unsigned pk4_fp8(unsigned a, unsigned b) {
  float2 fa = __half22float2(*(__half2*)&a);
  float2 fb = __half22float2(*(__half2*)&b);
  return enc1_fp8(fa.x) | (enc1_fp8(fa.y) << 8) | (enc1_fp8(fb.x) << 16) | (enc1_fp8(fb.y) << 24);
}
#endif

// ---------------- weight prep (layouts unchanged from R14) ----------------
__global__ void k_prep(const float* __restrict__ W_ah, const float* __restrict__ Wih_e,
                       const float* __restrict__ Whh_e, const float* __restrict__ W_d1,
                       const float* __restrict__ Wih_d, const float* __restrict__ Whh_d,
                       float* __restrict__ ws) {
  int idx = blockIdx.x * 512 + threadIdx.x;
  if (idx < 16384) {
    int k8 = idx >> 8, j = idx & 255;
    const float* wr = W_ah + (size_t)j * 512 + 8 * k8;
    union { __half2 h[4]; uint4 u; } w;
    w.h[0] = __floats2half2_rn(wr[0], wr[1]);
    w.h[1] = __floats2half2_rn(wr[2], wr[3]);
    w.h[2] = __floats2half2_rn(wr[4], wr[5]);
    w.h[3] = __floats2half2_rn(wr[6], wr[7]);
    ((uint4*)(ws + OFF_W8AH))[idx] = w.u;
  }
  if (idx < 16384) {
    int k8 = idx >> 8, j = idx & 255;
    const float* wr = W_d1 + (size_t)j * 768 + 8 * k8;
    union { __half2 h[4]; uint4 u; } w;
    w.h[0] = __floats2half2_rn(wr[0], wr[1]);
    w.h[1] = __floats2half2_rn(wr[2], wr[3]);
    w.h[2] = __floats2half2_rn(wr[4], wr[5]);
    w.h[3] = __floats2half2_rn(wr[6], wr[7]);
    ((uint4*)(ws + OFF_W8D1))[idx] = w.u;
  }
  if (idx < 43264) {
    int k2 = idx >> 8, j = idx & 255;
    auto we = [&](int g, int kk) -> float {
      if (kk < 81)  return Wih_e[(g * 256 + j) * 81 + kk];
      if (kk < 337) return Whh_e[(g * 256 + j) * 256 + (kk - 81)];
      return 0.f;
    };
    int ke = 2 * k2, ko = 2 * k2 + 1;
    union { __half2 h[4]; uint4 u; } w;
    w.h[0] = __floats2half2_rn(we(0, ke), we(0, ko));
    w.h[1] = __floats2half2_rn(we(1, ke), we(1, ko));
    w.h[2] = __floats2half2_rn(we(2, ke), we(2, ko));
    w.h[3] = __floats2half2_rn(we(3, ke), we(3, ko));
    ((uint4*)(ws + OFF_WE8))[idx] = w.u;
  }
  if (idx < 32768) {
    int r = idx >> 8, j = idx & 255;
    int gate = r >> 5, k8 = r & 31;
    const float* wr = Whh_d + (size_t)(gate * 256 + j) * 256 + 8 * k8;
    union { __half2 h[4]; uint4 u; } w;
    w.h[0] = __floats2half2_rn(wr[0], wr[1]);
    w.h[1] = __floats2half2_rn(wr[2], wr[3]);
    w.h[2] = __floats2half2_rn(wr[4], wr[5]);
    w.h[3] = __floats2half2_rn(wr[6], wr[7]);
    ((uint4*)(ws + OFF_WD8G))[idx] = w.u;
  }
}

// ---------------- attn_in[b][m] ----------------
__global__ void k_attn(const float* __restrict__ x, const float* __restrict__ W_ai,
                       const float* __restrict__ b_ai, float* __restrict__ ws) {
  __shared__ float wai[256];
  const int b = blockIdx.x, tid = threadIdx.x;  // 128 threads
  wai[tid] = W_ai[tid];
  wai[128 + tid] = W_ai[128 + tid];
  __syncthreads();
  if (tid < MM) {
    float acc = b_ai[0];
    const float* xp = x + (size_t)b * TT * MM + tid;
    #pragma unroll 8
    for (int t = 0; t < TT; ++t) acc = fmaf(xp[t * MM], wai[t], acc);
    ws[OFF_ATTN + b * MM + tid] = acc;
  }
}

// ---------------- encoder: 1024 threads, 2 batch rows, 256 steps ----------------
__global__ __launch_bounds__(1024, 2) void k_encoder(
    const float* __restrict__ x, const float* __restrict__ b_ah,
    const float* __restrict__ W_a, const float* __restrict__ b_a,
    const float* __restrict__ bih_e, const float* __restrict__ bhh_e,
    float* __restrict__ ws) {
  __shared__ __align__(16) float aA[2048];
  __shared__ __align__(16) float4 gA[2048];
  __shared__ __align__(16) float hpb[512];
  __shared__ __align__(16) float wa2m[256];    // -2*W_a
  __shared__ __align__(16) ushort hcb[2][512];
  __shared__ __align__(16) ushort uu[2][344];
  const int tid = threadIdx.x;
  const int j = tid & 255, q = tid >> 8;
  const int b0 = blockIdx.x * 2, b1 = b0 + 1;

  if (tid < 256) wa2m[tid] = -2.f * W_a[tid];
  if (tid < 512) { hcb[0][tid] = 0; hcb[1][tid] = 0; }
  if (tid < 344) { uu[0][tid] = 0; uu[1][tid] = 0; }
  float bahr = 0.f; float4 bias4 = {0, 0, 0, 0};
  if (tid < 512) {
    bahr = b_ah[j];
    bias4.x = bih_e[j] + bhh_e[j];
    bias4.y = bih_e[256 + j] + bhh_e[256 + j];
    bias4.z = bih_e[512 + j] + bhh_e[512 + j];
    bias4.w = bih_e[768 + j] + bhh_e[768 + j];
  }
  float ai0 = 0.f, ai1 = 0.f;
  {
    int m = tid & 127;
    if (m < MM) {
      ai0 = ws[OFF_ATTN + b0 * MM + m];
      ai1 = ws[OFF_ATTN + b1 * MM + m];
    }
  }
  const float bav = b_a[0];
  float xc0 = 0.f, xc1 = 0.f;
  if (tid < 128) {
    int bb = (tid >= 64) ? b1 : b0;
    int lane = tid & 63;
    xc0 = x[((size_t)bb * TT) * MM + lane];
    xc1 = (lane < 17) ? x[((size_t)bb * TT) * MM + 64 + lane] : 0.f;
  }
  const uint4* __restrict__ W8A = (const uint4*)(ws + OFF_W8AH);
  const uint4* __restrict__ We8 = (const uint4*)(ws + OFF_WE8);
  const uint4* __restrict__ hcq0 = (const uint4*)hcb[0];
  const uint4* __restrict__ hcq1 = (const uint4*)hcb[1];
  const unsigned int* __restrict__ u0p = (const unsigned int*)uu[0];
  const unsigned int* __restrict__ u1p = (const unsigned int*)uu[1];
  float creg = 0.f;
  __syncthreads();
  // bavw = b_a + sum_t W_a  (constant fold of the -2 trick)
  float bavw = bav;
  if (tid < 128) {
    float s = 0.f;
    #pragma unroll
    for (int i = 0; i < 64; ++i) {
      float4 v = *(const float4*)&wa2m[4 * i];
      s += v.x + v.y + v.z + v.w;
    }
    bavw = bav - 0.5f * s;
  }

  for (int t = 0; t < TT; ++t) {
    // ---- A: p1 partials (split accumulators) + LSTM h-part partials ----
    {
      float a0 = 0.f, a0b = 0.f, a1 = 0.f, a1b = 0.f;
      const int k8b = q * 16;
      #pragma unroll 4
      for (int i = 0; i < 16; ++i) {
        int k8 = k8b + i;
        uint4 wu = W8A[k8 * 256 + j];
        uint4 h0 = hcq0[k8], h1 = hcq1[k8];
        a0  = fdot2f(wu.x, h0.x, a0);  a0b = fdot2f(wu.y, h0.y, a0b);
        a0  = fdot2f(wu.z, h0.z, a0);  a0b = fdot2f(wu.w, h0.w, a0b);
        a1  = fdot2f(wu.x, h1.x, a1);  a1b = fdot2f(wu.y, h1.y, a1b);
        a1  = fdot2f(wu.z, h1.z, a1);  a1b = fdot2f(wu.w, h1.w, a1b);
      }
      aA[(q * 256 + j) * 2 + 0] = a0 + a0b;
      aA[(q * 256 + j) * 2 + 1] = a1 + a1b;
      float4 g0 = {0, 0, 0, 0}, g1 = {0, 0, 0, 0};
      const int ku0 = 41 + q * 32;
      #pragma unroll 4
      for (int i = 0; i < 32; ++i) {
        int ku = ku0 + i;
        uint4 wu = We8[ku * 256 + j];
        unsigned int ua = u0p[ku], ub = u1p[ku];
        g0.x = fdot2f(wu.x, ua, g0.x); g0.y = fdot2f(wu.y, ua, g0.y);
        g0.z = fdot2f(wu.z, ua, g0.z); g0.w = fdot2f(wu.w, ua, g0.w);
        g1.x = fdot2f(wu.x, ub, g1.x); g1.y = fdot2f(wu.y, ub, g1.y);
        g1.z = fdot2f(wu.z, ub, g1.z); g1.w = fdot2f(wu.w, ub, g1.w);
      }
      gA[(q * 2 + 0) * 256 + j] = g0;
      gA[(q * 2 + 1) * 256 + j] = g1;
    }
    __syncthreads();
    if (tid < 512) {
      int b = tid >> 8, h = tid & 255;
      hpb[2 * h + b] = aA[(0 * 256 + h) * 2 + b] + aA[(1 * 256 + h) * 2 + b] +
                       aA[(2 * 256 + h) * 2 + b] + aA[(3 * 256 + h) * 2 + b] + bahr;
    }
    __syncthreads();
    // ---- C: score[m] partials via -2w*rr with split accumulators ----
    {
      int m = tid & 127, tq = tid >> 7;
      if (m < MM) {
        float e0a = 0.f, e0b = 0.f, e1a = 0.f, e1b = 0.f;
        #pragma unroll 4
        for (int i = tq * 16; i < tq * 16 + 16; ++i) {
          float4 hv = *(const float4*)&hpb[i * 4];
          float2 wv = *(const float2*)&wa2m[i * 2];
          e0a = fmaf(wv.x, rrf(hv.x + ai0), e0a);
          e0b = fmaf(wv.y, rrf(hv.z + ai0), e0b);
          e1a = fmaf(wv.x, rrf(hv.y + ai1), e1a);
          e1b = fmaf(wv.y, rrf(hv.w + ai1), e1b);
        }
        aA[(tq * 2 + 0) * 96 + m] = e0a + e0b;
        aA[(tq * 2 + 1) * 96 + m] = e1a + e1b;
      }
    }
    __syncthreads();
    // ---- D: softmax over m + wi fp16 writes ----
    if (tid < 128) {
      int wv_id = tid >> 6, lane = tid & 63;
      float v0 = bavw, v1 = bavw;
      #pragma unroll
      for (int tq = 0; tq < 8; ++tq) {
        v0 += aA[(tq * 2 + wv_id) * 96 + lane];
        if (lane < 17) v1 += aA[(tq * 2 + wv_id) * 96 + 64 + lane];
      }
      float e0 = __expf(v0);
      float e1 = (lane < 17) ? __expf(v1) : 0.f;
      float sm = e0 + e1;
      #pragma unroll
      for (int d = 1; d < 64; d <<= 1) sm += __shfl_xor(sm, d);
      float inv = frcp(sm);
      uu[wv_id][lane] = f2h(e0 * inv * xc0);
      if (lane < 17) uu[wv_id][64 + lane] = f2h(e1 * inv * xc1);
      if (t < 255) {
        int bb = wv_id ? b1 : b0;
        xc0 = x[((size_t)bb * TT + t + 1) * MM + lane];
        xc1 = (lane < 17) ? x[((size_t)bb * TT + t + 1) * MM + 64 + lane] : 0.f;
      }
    }
    __syncthreads();
    // ---- E: LSTM wi-part partials ----
    {
      const int kA = (q == 0) ? 0 : (q == 1) ? 11 : (q == 2) ? 21 : 31;
      const int kB = (q == 0) ? 11 : (q == 1) ? 21 : (q == 2) ? 31 : 41;
      float4 g0 = gA[(q * 2 + 0) * 256 + j];
      float4 g1 = gA[(q * 2 + 1) * 256 + j];
      for (int ku = kA; ku < kB; ++ku) {
        uint4 wu = We8[ku * 256 + j];
        unsigned int ua = u0p[ku], ub = u1p[ku];
        g0.x = fdot2f(wu.x, ua, g0.x); g0.y = fdot2f(wu.y, ua, g0.y);
        g0.z = fdot2f(wu.z, ua, g0.z); g0.w = fdot2f(wu.w, ua, g0.w);
        g1.x = fdot2f(wu.x, ub, g1.x); g1.y = fdot2f(wu.y, ub, g1.y);
        g1.z = fdot2f(wu.z, ub, g1.z); g1.w = fdot2f(wu.w, ub, g1.w);
      }
      gA[(q * 2 + 0) * 256 + j] = g0;
      gA[(q * 2 + 1) * 256 + j] = g1;
    }
    __syncthreads();
    // ---- F: gate combine + state update ----
    if (tid < 512) {
      int b = tid >> 8, jj = tid & 255;
      float4 s0 = gA[(0 * 2 + b) * 256 + jj];
      float4 s1 = gA[(1 * 2 + b) * 256 + jj];
      float4 s2 = gA[(2 * 2 + b) * 256 + jj];
      float4 s3 = gA[(3 * 2 + b) * 256 + jj];
      float gi = s0.x + s1.x + s2.x + s3.x + bias4.x;
      float gf = s0.y + s1.y + s2.y + s3.y + bias4.y;
      float gg = s0.z + s1.z + s2.z + s3.z + bias4.z;
      float go = s0.w + s1.w + s2.w + s3.w + bias4.w;
      float c = fsig(gf) * creg + fsig(gi) * ftanh(gg);
      float h = fsig(go) * ftanh(c);
      creg = c;
      hcb[b][jj] = f2h(h);
      hcb[b][256 + jj] = f2h(c);
      uu[b][81 + jj] = f2h(h);
      ws[OFF_ENC + (((size_t)(b ? b1 : b0) * TT + t) * HEE + jj)] = h;
    }
    __syncthreads();
  }
}

// ---------------- encW[b][t] = enc[b,t,:] . W_fc[:256] ----------------
__global__ __launch_bounds__(256) void k_encw(const float* __restrict__ W_fc, float* __restrict__ ws) {
  const float* __restrict__ enc = ws + OFF_ENC;
  const int wv = threadIdx.x >> 6, lane = threadIdx.x & 63;
  float4 wfc = reinterpret_cast<const float4*>(W_fc)[lane];
  for (int r = blockIdx.x * 4 + wv; r < BB * TT; r += 4096) {
    float4 e = reinterpret_cast<const float4*>(enc + (size_t)r * HEE)[lane];
    float d = e.x * wfc.x + e.y * wfc.y + e.z * wfc.z + e.w * wfc.w;
    #pragma unroll
    for (int dd = 1; dd < 64; dd <<= 1) d += __shfl_xor(d, dd);
    if (lane == 0) ws[OFF_ENCW + r] = d;
  }
}

// ---------------- enc_proj fp16: epH[b][t'][h] ----------------
__global__ __launch_bounds__(256) void k_encproj(const float* __restrict__ W_d1, float* __restrict__ ws) {
  __shared__ __align__(16) float le[16][256];
  const int tid = threadIdx.x;
  const int b = blockIdx.x >> 4;
  const int t0 = (blockIdx.x & 15) * 16;
  const float* __restrict__ enc = ws + OFF_ENC;
  __half* __restrict__ epH = (__half*)(ws + OFF_EPI);
  #pragma unroll
  for (int rr = 0; rr < 16; ++rr)
    le[rr][tid] = enc[((size_t)b * TT + (t0 + rr)) * HEE + tid];
  __syncthreads();
  const float4* wrow = (const float4*)(W_d1 + (size_t)tid * 768 + 512);
  float acc[16];
  #pragma unroll
  for (int r = 0; r < 16; ++r) acc[r] = 0.f;
  for (int e4 = 0; e4 < 64; ++e4) {
    float4 w = wrow[e4];
    #pragma unroll
    for (int r = 0; r < 16; ++r) {
      float4 ev = *(const float4*)&le[r][e4 * 4];
      acc[r] += ev.x * w.x + ev.y * w.y + ev.z * w.z + ev.w * w.w;
    }
  }
  #pragma unroll
  for (int rr = 0; rr < 16; ++rr)
    epH[((size_t)b * TT + (t0 + rr)) * HEE + tid] = __float2half(acc[rr]);
}

// ---------------- decoder: 512 WGs x 1024 threads, 1 batch/WG, 2 WGs/CU, anti-phase ----------------
__global__ __launch_bounds__(1024, 8) void k_decoder(
    const float* __restrict__ y_history, const float* __restrict__ b_d1,
    const float* __restrict__ W_d2, const float* __restrict__ b_d2,
    const float* __restrict__ W_fc, const float* __restrict__ b_fc,
    const float* __restrict__ Wih_d,
    const float* __restrict__ bih_d, const float* __restrict__ bhh_d,
    const float* __restrict__ W_ff, const float* __restrict__ b_ff,
    float* __restrict__ ws, float* __restrict__ out) {
  __shared__ __align__(16) unsigned char ep8L[65536]; // fp8 ep, swizzled (64 KB)
  __shared__ __align__(16) float aA[1024];
  __shared__ __align__(16) float gL[1024];
  __shared__ __align__(16) float ddp[256];
  __shared__ __align__(16) ushort hc[512];
  __shared__ __align__(16) float w2m[256];     // -2*W_d2
  __shared__ __align__(16) float ybuf[256];
  __shared__ float red[2][4];
  const int tid = threadIdx.x;
  const int tp = tid & 255, q = tid >> 8;
  const int lane = tid & 63, wvid = tid >> 6;
  const int b = blockIdx.x;
  const float wfcy = W_fc[256], bfc = b_fc[0], bd2v = b_d2[0], bffv = b_ff[0];

  // ---- anti-phase stagger: de-phase the two co-resident WGs by ~half a step.
  // Parity (bit0 ^ bit8) differs for the CU-sharing pair under both pairwise
  // (2i,2i+1) and fill-then-wrap (k,k+256) blockIdx->CU mappings.
  if (((blockIdx.x ^ (blockIdx.x >> 8)) & 1) != 0) {
    unsigned long long t0 = __builtin_amdgcn_s_memrealtime();
    while (__builtin_amdgcn_s_memrealtime() - t0 < 1200ULL) {}  // ~12 us @100 MHz
  }

  if (tid < 256) w2m[tid] = -2.f * W_d2[tid];
  if (tid < 512) hc[tid] = 0;
  if (tid < 255) ybuf[tid] = y_history[(size_t)b * 255 + tid] * wfcy + bfc;
  const float bd1r = b_d1[tp];
  float4 biasd, wy;
  biasd.x = bih_d[tp] + bhh_d[tp];
  biasd.y = bih_d[256 + tp] + bhh_d[256 + tp];
  biasd.z = bih_d[512 + tp] + bhh_d[512 + tp];
  biasd.w = bih_d[768 + tp] + bhh_d[768 + tp];
  wy.x = Wih_d[tp]; wy.y = Wih_d[256 + tp]; wy.z = Wih_d[512 + tp]; wy.w = Wih_d[768 + tp];
  const float wffh = W_ff[tp], wffc = W_ff[256 + tp];
  const float ewr = ws[OFF_ENCW + (size_t)b * 256 + tp];

  const uint4* __restrict__ W8 = (const uint4*)(ws + OFF_W8D1);
  const uint4* __restrict__ WG = (const uint4*)(ws + OFF_WD8G);
  const uint4* __restrict__ epg = (const uint4*)(ws + OFF_EPI);
  const uint4* __restrict__ ep16 = (const uint4*)ep8L;
  const uint4* __restrict__ hc4 = (const uint4*)hc;

  {
    #pragma unroll
    for (int k = 0; k < 4; ++k) {
      int g = k * 1024 + tid;
      int t = g >> 4, c = g & 15;
      const uint4* src = epg + (size_t)b * 8192 + t * 32 + c * 2;
      uint4 lo = src[0], hi = src[1];
      uint4 o;
      o.x = pk4_fp8(lo.x, lo.y);
      o.y = pk4_fp8(lo.z, lo.w);
      o.z = pk4_fp8(hi.x, hi.y);
      o.w = pk4_fp8(hi.z, hi.w);
      ((uint4*)ep8L)[(g & ~15) | (c ^ (t & 15))] = o;
    }
  }
  const uint4* __restrict__ epXg = epg + (size_t)b * 8192 + tp * 32 + q * 8;
  __syncthreads();
  // bd2w = b_d2 + sum_h W_d2 (constant fold of -2 trick)
  float bd2w = bd2v;
  if (tid < 256) {
    float s = 0.f;
    #pragma unroll
    for (int i = 0; i < 64; ++i) {
      float4 v = *(const float4*)&w2m[4 * i];
      s += v.x + v.y + v.z + v.w;
    }
    bd2w = bd2v - 0.5f * s;
  }

  float hreg = 0.f, creg = 0.f;
  float escls = 0.f, invls = 0.f, esc = 0.f;

  for (int s = 0; s < 255; ++s) {
    // ---- A: p1 partial (4 acc chains) + one full gate per thread (4 acc chains) ----
    {
      float a0 = 0.f, a1 = 0.f, a2 = 0.f, a3 = 0.f;
      const int k8b = q * 16;
      #pragma unroll 4
      for (int i = 0; i < 16; ++i) {
        int k8 = k8b + i;
        uint4 wu = W8[k8 * 256 + tp];
        uint4 hv = hc4[k8];
        a0 = fdot2f(wu.x, hv.x, a0); a1 = fdot2f(wu.y, hv.y, a1);
        a2 = fdot2f(wu.z, hv.z, a2); a3 = fdot2f(wu.w, hv.w, a3);
      }
      aA[q * 256 + tp] = (a0 + a1) + (a2 + a3);
      float g0 = 0.f, g1 = 0.f, g2 = 0.f, g3 = 0.f;
      const uint4* wg = WG + (q * 32) * 256 + tp;
      #pragma unroll 4
      for (int i = 0; i < 32; ++i) {
        uint4 wu = wg[i * 256];
        uint4 hv = hc4[i];
        g0 = fdot2f(wu.x, hv.x, g0); g1 = fdot2f(wu.y, hv.y, g1);
        g2 = fdot2f(wu.z, hv.z, g2); g3 = fdot2f(wu.w, hv.w, g3);
      }
      gL[q * 256 + tp] = (g0 + g1) + (g2 + g3);
    }
    __syncthreads();
    // ---- B: d combine ----
    if (tid < 256)
      ddp[tid] = aA[tid] + aA[256 + tid] + aA[512 + tid] + aA[768 + tid] + bd1r;
    __syncthreads();
    // ---- C: score partials via -2w*rr (2 acc chains); exact fp16 at s==254 ----
    if (s != 254) {
      float q0 = 0.f, q1 = 0.f;
      const int base = tp * 16, sw = tp & 15;
      #pragma unroll
      for (int k = 0; k < 4; ++k) {
        uint4 eu = ep16[base + ((q * 4 + k) ^ sw)];
        const int hb = q * 64 + k * 16;
        const unsigned* ed = (const unsigned*)&eu;
        #pragma unroll
        for (int dd = 0; dd < 4; ++dd) {
          const int h4 = hb + dd * 4;
          float2 xa = cvt2lo(ed[dd]), xb = cvt2hi(ed[dd]);
          float4 wf = *(const float4*)&w2m[h4];
          float4 dv = *(const float4*)&ddp[h4];
          q0 = fmaf(wf.x, rrf(xa.x + dv.x), q0);
          q1 = fmaf(wf.y, rrf(xa.y + dv.y), q1);
          q0 = fmaf(wf.z, rrf(xb.x + dv.z), q0);
          q1 = fmaf(wf.w, rrf(xb.y + dv.w), q1);
        }
      }
      aA[q * 256 + tp] = q0 + q1;
    } else {
      float q0 = 0.f, q1 = 0.f;
      #pragma unroll
      for (int k = 0; k < 8; ++k) {
        uint4 eu = epXg[k];
        const int h8 = q * 64 + k * 8;
        const __half2* eh = (const __half2*)&eu;
        #pragma unroll
        for (int jj = 0; jj < 4; ++jj) {
          float2 ea = __half22float2(eh[jj]);
          float2 wf = *(const float2*)&w2m[h8 + 2 * jj];
          float2 dv = *(const float2*)&ddp[h8 + 2 * jj];
          q0 = fmaf(wf.x, rrf(ea.x + dv.x), q0);
          q1 = fmaf(wf.y, rrf(ea.y + dv.y), q1);
        }
      }
      aA[q * 256 + tp] = q0 + q1;
    }
    __syncthreads();
    // ---- D: softmax partial reductions (no max-shift) ----
    if (tid < 256) {
      float v = aA[tp] + aA[256 + tp] + aA[512 + tp] + aA[768 + tp] + bd2w;
      esc = __expf(v);
      float den = esc, num = esc * ewr;
      #pragma unroll
      for (int d = 1; d < 64; d <<= 1) { den += __shfl_xor(den, d); num += __shfl_xor(num, d); }
      if (lane == 0) { red[0][wvid] = den; red[1][wvid] = num; }
    }
    __syncthreads();
    // ---- E: y + gate combine + state update ----
    if (tid < 256) {
      float den = red[0][0] + red[0][1] + red[0][2] + red[0][3];
      float num = red[1][0] + red[1][1] + red[1][2] + red[1][3];
      float inv = frcp(den);
      float y = num * inv + ybuf[s];
      if (s == 254) { escls = esc; invls = inv; }
      float gi = gL[tp]       + wy.x * y + biasd.x;
      float gf = gL[256 + tp] + wy.y * y + biasd.y;
      float gg = gL[512 + tp] + wy.z * y + biasd.z;
      float go = gL[768 + tp] + wy.w * y + biasd.w;
      float c = fsig(gf) * creg + fsig(gi) * ftanh(gg);
      float h = fsig(go) * ftanh(c);
      creg = c; hreg = h;
      hc[tp] = f2h(h);
      hc[256 + tp] = f2h(c);
    }
    __syncthreads();
  }

  // ---- finale: last-step aw + ctx + output ----
  if (tid < 256) ddp[tp] = escls * invls;
  __syncthreads();
  {
    float c0 = 0.f;
    const float* __restrict__ e32 = ws + OFF_ENC + (size_t)b * TT * HEE;
    for (int t = q * 64; t < q * 64 + 64; ++t)
      c0 = fmaf(ddp[t], e32[(size_t)t * HEE + tp], c0);
    __syncthreads();
    aA[q * 256 + tp] = c0;
  }
  __syncthreads();
  if (tid < 256) {
    float ctx = aA[tp] + aA[256 + tp] + aA[512 + tp] + aA[768 + tp];
    float p = hreg * wffh + ctx * wffc;
    #pragma unroll
    for (int d = 1; d < 64; d <<= 1) p += __shfl_xor(p, d);
    if (lane == 0) red[0][wvid] = p;
  }
  __syncthreads();
  if (tid == 0) out[b] = red[0][0] + red[0][1] + red[0][2] + red[0][3] + bffv;
}

extern "C" void kernel_launch(void* const* d_in, const int* in_sizes, int n_in,
                              void* d_out, int out_size, void* d_ws, size_t ws_size,
                              hipStream_t stream) {
  if (ws_size < (size_t)WS_FLOATS * sizeof(float)) return;
  const float* x     = (const float*)d_in[0];
  const float* y_h   = (const float*)d_in[1];
  const float* W_ah  = (const float*)d_in[2];
  const float* b_ah  = (const float*)d_in[3];
  const float* W_ai  = (const float*)d_in[4];
  const float* b_ai  = (const float*)d_in[5];
  const float* W_a   = (const float*)d_in[6];
  const float* b_a   = (const float*)d_in[7];
  const float* Wih_e = (const float*)d_in[8];
  const float* Whh_e = (const float*)d_in[9];
  const float* bih_e = (const float*)d_in[10];
  const float* bhh_e = (const float*)d_in[11];
  const float* W_d1  = (const float*)d_in[12];
  const float* b_d1  = (const float*)d_in[13];
  const float* W_d2  = (const float*)d_in[14];
  const float* b_d2  = (const float*)d_in[15];
  const float* W_fc  = (const float*)d_in[16];
  const float* b_fc  = (const float*)d_in[17];
  const float* Wih_d = (const float*)d_in[18];
  const float* Whh_d = (const float*)d_in[19];
  const float* bih_d = (const float*)d_in[20];
  const float* bhh_d = (const float*)d_in[21];
  const float* W_ff  = (const float*)d_in[22];
  const float* b_ff  = (const float*)d_in[23];
  float* ws  = (float*)d_ws;
  float* out = (float*)d_out;

  k_prep<<<256, 512, 0, stream>>>(W_ah, Wih_e, Whh_e, W_d1, Wih_d, Whh_d, ws);
  k_attn<<<512, 128, 0, stream>>>(x, W_ai, b_ai, ws);
  k_encoder<<<256, 1024, 0, stream>>>(x, b_ah, W_a, b_a, bih_e, bhh_e, ws);
  k_encw<<<1024, 256, 0, stream>>>(W_fc, ws);
  k_encproj<<<8192, 256, 0, stream>>>(W_d1, ws);
  k_decoder<<<512, 1024, 0, stream>>>(y_h, b_d1, W_d2, b_d2, W_fc, b_fc,
                                      Wih_d, bih_d, bhh_d, W_ff, b_ff, ws, out);
}